// Round 5
// baseline (586.154 us; speedup 1.0000x reference)
//
#include <hip/hip_runtime.h>
#include <stdint.h>

typedef unsigned short u16;
typedef __bf16 bf16_t;
typedef bf16_t bf16x8 __attribute__((ext_vector_type(8)));
typedef float f32x4 __attribute__((ext_vector_type(4)));

#define E_DIM 1536
#define N_B 8
#define L_SEQ 2048
#define NT 2046
#define SCALE 0.025515518f   // 1/sqrt(1536)
#define LN_EPS 1e-5f

__device__ __forceinline__ u16 f2b(float f) {
  union { float f; uint32_t u; } v; v.f = f;
  uint32_t u = v.u + 0x7FFFu + ((v.u >> 16) & 1u);  // RNE
  return (u16)(u >> 16);
}
__device__ __forceinline__ float b2f(u16 h) {
  union { uint32_t u; float f; } v; v.u = ((uint32_t)h) << 16; return v.f;
}

// async global->LDS, 16B per lane; LDS dest = wave-uniform base + lane*16
__device__ __forceinline__ void gload16(const u16* g, const bf16_t* l) {
  __builtin_amdgcn_global_load_lds((const __attribute__((address_space(1))) void*)g,
                                   (__attribute__((address_space(3))) void*)l,
                                   16, 0, 0);
}

#define BAR()   __builtin_amdgcn_s_barrier()
#define SCHB()  __builtin_amdgcn_sched_barrier(0)
#define LG0()   asm volatile("s_waitcnt lgkmcnt(0)" ::: "memory")
#define LG4()   asm volatile("s_waitcnt lgkmcnt(4)" ::: "memory")
#define LG8()   asm volatile("s_waitcnt lgkmcnt(8)" ::: "memory")
#define VM8()   asm volatile("s_waitcnt vmcnt(8)" ::: "memory")
#define VM4()   asm volatile("s_waitcnt vmcnt(4)" ::: "memory")
#define VM0()   asm volatile("s_waitcnt vmcnt(0)" ::: "memory")

// ---------------- f32 -> bf16 conversion (vectorized) ----------------
__global__ void cvt_kernel(const float* __restrict__ in, u16* __restrict__ out, int nvec) {
  int i = blockIdx.x * 256 + threadIdx.x;
  if (i < nvec) {
    float4 f = ((const float4*)in)[i];
    ushort4 u;
    u.x = f2b(f.x); u.y = f2b(f.y); u.z = f2b(f.z); u.w = f2b(f.w);
    ((ushort4*)out)[i] = u;
  }
}

// ---------------- 256x256 lookahead-pipelined bf16 GEMM ----------------
// C[i][j] = sum_k A[i][k]*B[j][k].  BM=BN=256, BK=64 (kk0/kk1), 8 waves
// (2Mx4N), 512 thr, 128KB dyn LDS = 4-slot ring of 32-K units (unit u ->
// slot u&3; A at slot*8192, B at 32768+slot*8192).
// 4 phases/tile; phase p ISSUES the ds_reads for phase p+1's fragments,
// then gates with COUNTED lgkmcnt (waits only phase p's frags) so p+1's
// LDS drain overlaps p's MFMA.  A frags double-buffer per phase (aC/aN),
// B per K-half (bC/bN).  Staging: whole unit (4 gloads) at p0 (unit 2t+3)
// and p2 (unit 2t+4).  vmcnt ledger (units of 4 loads, steady tt):
//   p0-end VM8 retires 4tt+1 (slot1, read by p1)   [staged 4 phases ago]
//   p2-end VM8 retires 4tt+2 (slot2, read by p3)
//   t1 p0-end VM8 retires 4tt+3; t1 p2-end VM8 retires 4tt+4
// lgkm gates: queue=[prev-phase reads, this-phase reads]; wait to
// this-phase count (4 or 8) -> prev phase's frags complete.
// Overwrite safety: every staged slot's readers retired at a prior
// lgkm gate + barrier (verified per slot).  Tail peeled (tiles 22,23):
// VM8 / VM4 / VM0 / none; final gate LG0.
template<int FUSED>
__launch_bounds__(512, 2)
__global__ void gemml(const u16* __restrict__ Ag,
                      const u16* __restrict__ B0w, const u16* __restrict__ B1w,
                      const u16* __restrict__ B2w,
                      u16* __restrict__ C0, u16* __restrict__ C1, u16* __restrict__ C2,
                      float* __restrict__ Cf, const float* __restrict__ bias,
                      const float* __restrict__ resid)
{
  extern __shared__ __attribute__((aligned(16))) bf16_t lds[];

  // --- bijective XCD remap: 24-block groups (4 row-strips x 6 col-tiles)
  const int flat = (blockIdx.z * gridDim.y + blockIdx.y) * gridDim.x + blockIdx.x;
  const int xcd = flat & 7, bb_ = flat >> 3;
  const int gl = bb_ / 24, jj = bb_ % 24;
  const int g = gl * 8 + xcd;
  const int zz = g >> 4;
  const int gy = g & 15;
  const int tx = jj >> 2;
  const int ty = gy * 4 + (jj & 3);
  const int rowA = ty * 256, colB = tx * 256;

  const u16* Bg; u16* Cb;
  if (zz == 0)      { Bg = B0w; Cb = C0; }
  else if (zz == 1) { Bg = B1w; Cb = C1; }
  else              { Bg = B2w; Cb = C2; }

  const int tid = threadIdx.x;
  const int w = tid >> 6, lane = tid & 63;
  const int wr = w >> 2, wc = w & 3;

  // fragment read addressing (swizzled slot): row=64B, slot ^= (r>>1)&3
  const int rl = lane & 15, lsl = lane >> 4;
  const int sw8 = (lsl ^ ((rl >> 1) & 3)) * 8;
  const int arow = (wr * 128 + rl) * 32 + sw8;   // + m*512 + slot*8192
  const int brow = (wc * 64 + rl) * 32 + sw8;    // + n*512 + 32768+slot*8192

  // staging: chunk c = tid; r=c>>2, sp=c&3; source pre-swizzled so the
  // linear LDS dest holds the swizzled layout (rule 21).
  const int r0s = tid >> 2, sps = tid & 3;
  const int sws = (sps ^ ((r0s >> 1) & 3)) * 8;
  const size_t sA0 = (size_t)(rowA + r0s) * E_DIM + sws;
  const size_t sA1 = (size_t)(rowA + 128 + r0s) * E_DIM + sws;
  const size_t sB0 = (size_t)(colB + r0s) * E_DIM + sws;
  const size_t sB1 = (size_t)(colB + 128 + r0s) * E_DIM + sws;
  const int wb0 = w * 512, wb1 = 4096 + w * 512;   // elem offsets in region

  f32x4 acc[8][4];
#pragma unroll
  for (int m = 0; m < 8; ++m)
#pragma unroll
    for (int n = 0; n < 4; ++n)
#pragma unroll
      for (int q = 0; q < 4; ++q) acc[m][n][q] = 0.0f;

  bf16x8 aC[4], aN[4], bC[4], bN[4];

  // stage unit un (32 K-cols at un*32) into ring slot (literal at call site)
  auto stageU = [&](int un, int slot) {
    const size_t ko = (size_t)un * 32;
    bf16_t* dA = lds + slot * 8192;
    bf16_t* dB = lds + 32768 + slot * 8192;
    gload16(Ag + sA0 + ko, dA + wb0);
    gload16(Ag + sA1 + ko, dA + wb1);
    gload16(Bg + sB0 + ko, dB + wb0);
    gload16(Bg + sB1 + ko, dB + wb1);
  };
  auto rdA = [&](bf16x8 (&d)[4], int slot, int mh) {
#pragma unroll
    for (int i = 0; i < 4; ++i)
      d[i] = *(const bf16x8*)&lds[slot * 8192 + arow + (mh * 4 + i) * 512];
  };
  auto rdB = [&](bf16x8 (&d)[4], int slot) {
#pragma unroll
    for (int n = 0; n < 4; ++n)
      d[n] = *(const bf16x8*)&lds[32768 + slot * 8192 + brow + n * 512];
  };
  auto mf = [&](const bf16x8 (&a)[4], const bf16x8 (&b)[4], int mh) {
    __builtin_amdgcn_s_setprio(1);
#pragma unroll
    for (int i = 0; i < 4; ++i)
#pragma unroll
      for (int n = 0; n < 4; ++n)
        acc[mh * 4 + i][n] =
            __builtin_amdgcn_mfma_f32_16x16x32_bf16(a[i], b[n], acc[mh * 4 + i][n], 0, 0, 0);
    __builtin_amdgcn_s_setprio(0);
  };

  // ---- prologue: units 0,1,2 -> slots 0,1,2; retire unit0; read t0 frags
  stageU(0, 0); stageU(1, 1); stageU(2, 2);
  VM8();
  BAR();
  rdA(aC, 0, 0); rdB(bC, 0);

  // ---- steady: tiles 0..21 (2 per iteration; slots 0/1 then 2/3)
  for (int tt = 0; tt < 11; ++tt) {
    const int u3 = 4 * tt + 3, u4 = u3 + 1, u5 = u3 + 2, u6 = u3 + 3;
    // tile 2tt
    rdA(aN, 0, 1);              stageU(u3, 3);  BAR(); LG4(); SCHB(); mf(aC, bC, 0); VM8(); BAR();
    rdA(aC, 1, 0); rdB(bN, 1);                  BAR(); LG8(); SCHB(); mf(aN, bC, 1);        BAR();
    rdA(aN, 1, 1);              stageU(u4, 0);  BAR(); LG4(); SCHB(); mf(aC, bN, 0); VM8(); BAR();
    rdA(aC, 2, 0); rdB(bC, 2);                  BAR(); LG8(); SCHB(); mf(aN, bN, 1);        BAR();
    // tile 2tt+1
    rdA(aN, 2, 1);              stageU(u5, 1);  BAR(); LG4(); SCHB(); mf(aC, bC, 0); VM8(); BAR();
    rdA(aC, 3, 0); rdB(bN, 3);                  BAR(); LG8(); SCHB(); mf(aN, bC, 1);        BAR();
    rdA(aN, 3, 1);              stageU(u6, 2);  BAR(); LG4(); SCHB(); mf(aC, bN, 0); VM8(); BAR();
    rdA(aC, 0, 0); rdB(bC, 0);                  BAR(); LG8(); SCHB(); mf(aN, bN, 1);        BAR();
  }
  // ---- tail: tiles 22,23 (units 45,46,47 drain; 47 staged at t22 p0)
  rdA(aN, 0, 1);                stageU(47, 3);  BAR(); LG4(); SCHB(); mf(aC, bC, 0); VM8(); BAR();
  rdA(aC, 1, 0); rdB(bN, 1);                    BAR(); LG8(); SCHB(); mf(aN, bC, 1);        BAR();
  rdA(aN, 1, 1);                                BAR(); LG4(); SCHB(); mf(aC, bN, 0); VM4(); BAR();
  rdA(aC, 2, 0); rdB(bC, 2);                    BAR(); LG8(); SCHB(); mf(aN, bN, 1);        BAR();
  rdA(aN, 2, 1);                                BAR(); LG4(); SCHB(); mf(aC, bC, 0); VM0(); BAR();
  rdA(aC, 3, 0); rdB(bN, 3);                    BAR(); LG8(); SCHB(); mf(aN, bC, 1);        BAR();
  rdA(aN, 3, 1);                                BAR(); LG4(); SCHB(); mf(aC, bN, 0);        BAR();
                                                BAR(); LG0(); SCHB(); mf(aN, bN, 1);

  // ---- epilogue: C/D layout col=lane&15, row=(lane>>4)*4+reg [m89]
  const int r0 = (lane >> 4) * 4;
#pragma unroll
  for (int m = 0; m < 8; ++m) {
#pragma unroll
    for (int n = 0; n < 4; ++n) {
      const int gcol = colB + wc * 64 + n * 16 + rl;
#pragma unroll
      for (int q = 0; q < 4; ++q) {
        const int grow = rowA + wr * 128 + m * 16 + r0 + q;
        const size_t idx = (size_t)grow * E_DIM + gcol;
        if (FUSED) Cf[idx] = acc[m][n][q] + bias[gcol] + resid[idx];
        else       Cb[idx] = f2b(acc[m][n][q]);
      }
    }
  }
}

// ---------------- per-position 12x12 head-mix attention ----------------
__launch_bounds__(256)
__global__ void headmix(const u16* __restrict__ qb, const u16* __restrict__ kb,
                        const u16* __restrict__ vb, u16* __restrict__ aob)
{
  __shared__ float qs[12 * 132], ks2[12 * 132], vs[12 * 132];
  __shared__ float att[12][12];
  const int tid = threadIdx.x;
  const size_t base = (size_t)blockIdx.x * E_DIM;

  for (int e = tid; e < E_DIM; e += 256) {
    int i = e >> 7, d = e & 127, p = i * 132 + d;
    qs[p]  = b2f(qb[base + e]);
    ks2[p] = b2f(kb[base + e]);
    vs[p]  = b2f(vb[base + e]);
  }
  __syncthreads();

  if (tid < 144) {
    int i = tid / 12, j = tid % 12;
    float s = 0.f;
#pragma unroll 8
    for (int d = 0; d < 128; ++d) s += qs[i * 132 + d] * ks2[j * 132 + d];
    att[i][j] = s * SCALE;
  }
  __syncthreads();

  if (tid < 12) {
    float mx = att[tid][0];
#pragma unroll
    for (int j = 1; j < 12; ++j) mx = fmaxf(mx, att[tid][j]);
    float ev[12], sum = 0.f;
#pragma unroll
    for (int j = 0; j < 12; ++j) { ev[j] = expf(att[tid][j] - mx); sum += ev[j]; }
    float inv = 1.f / sum;
#pragma unroll
    for (int j = 0; j < 12; ++j) att[tid][j] = ev[j] * inv;
  }
  __syncthreads();

  for (int e = tid; e < E_DIM; e += 256) {
    int i = e >> 7, d = e & 127;
    float o = 0.f;
#pragma unroll
    for (int j = 0; j < 12; ++j) o += att[i][j] * vs[j * 132 + d];
    aob[base + e] = f2b(o);
  }
}

// ---------------- in-place LayerNorm over rows of 1536 ----------------
__launch_bounds__(256)
__global__ void ln_kernel(float* __restrict__ p, const float* __restrict__ gamma,
                          const float* __restrict__ beta)
{
  __shared__ float rs[4], rq[4];
  __shared__ float mean_s, rstd_s;
  const int tid = threadIdx.x, w = tid >> 6, lane = tid & 63;
  float* row = p + (size_t)blockIdx.x * E_DIM;

  float v[6], s = 0.f, sq = 0.f;
#pragma unroll
  for (int i = 0; i < 6; ++i) {
    v[i] = row[tid + i * 256];
    s += v[i]; sq += v[i] * v[i];
  }
#pragma unroll
  for (int off = 32; off > 0; off >>= 1) {
    s  += __shfl_down(s, off);
    sq += __shfl_down(sq, off);
  }
  if (lane == 0) { rs[w] = s; rq[w] = sq; }
  __syncthreads();
  if (tid == 0) {
    float S = rs[0] + rs[1] + rs[2] + rs[3];
    float Q = rq[0] + rq[1] + rq[2] + rq[3];
    float mu = S * (1.f / 1536.f);
    float var = Q * (1.f / 1536.f) - mu * mu;
    mean_s = mu; rstd_s = rsqrtf(var + LN_EPS);
  }
  __syncthreads();
  const float mu = mean_s, rstd = rstd_s;
#pragma unroll
  for (int i = 0; i < 6; ++i) {
    int e = tid + i * 256;
    row[e] = (v[i] - mu) * rstd * gamma[e] + beta[e];
  }
}

// ---------------- e_state = mean over L (two-stage, deterministic) ----------------
__global__ void estate_partial(const float* __restrict__ outp, float* __restrict__ part)
{
  const int e = blockIdx.x * 256 + threadIdx.x;  // grid.x = 6
  const int b = blockIdx.y, z = blockIdx.z;      // 8, 8
  const float* p = outp + ((size_t)b * L_SEQ + z * 256) * E_DIM + e;
  float acc = 0.f;
  for (int l = 0; l < 256; ++l) acc += p[(size_t)l * E_DIM];
  part[(size_t)(z * N_B + b) * E_DIM + e] = acc;
}
__global__ void estate_reduce(const float* __restrict__ part, float* __restrict__ est)
{
  const int i = blockIdx.x * 256 + threadIdx.x;  // 8*1536 = 12288
  if (i < N_B * E_DIM) {
    float s = 0.f;
#pragma unroll
    for (int z = 0; z < 8; ++z) s += part[(size_t)z * N_B * E_DIM + i];
    est[i] = s * (1.f / 2048.f);
  }
}

// ---------------- scores[b][s][t] = dot(e_state[s], out[b][2+t]) * SCALE ----------
__launch_bounds__(256)
__global__ void scores_kernel(const float* __restrict__ outp, const float* __restrict__ est,
                              float* __restrict__ wout)
{
  __shared__ float es[N_B * E_DIM];  // 48 KB
  const int tid = threadIdx.x, wv = tid >> 6, lane = tid & 63;
  const int b = blockIdx.y;
  for (int i = tid; i < N_B * E_DIM; i += 256) es[i] = est[i];
  __syncthreads();

  for (int ti = 0; ti < 16; ++ti) {
    int t = blockIdx.x * 64 + wv * 16 + ti;   // wave-uniform
    if (t >= NT) continue;
    const float* row = outp + ((size_t)b * L_SEQ + 2 + t) * E_DIM;
    float a[8];
#pragma unroll
    for (int s = 0; s < 8; ++s) a[s] = 0.f;
    for (int c = 0; c < 24; ++c) {
      int idx = c * 64 + lane;
      float val = row[idx];
#pragma unroll
      for (int s = 0; s < 8; ++s) a[s] += es[s * E_DIM + idx] * val;
    }
#pragma unroll
    for (int off = 32; off > 0; off >>= 1)
#pragma unroll
      for (int s = 0; s < 8; ++s) a[s] += __shfl_down(a[s], off);
    if (lane == 0) {
#pragma unroll
      for (int s = 0; s < 8; ++s)
        wout[(size_t)(b * N_B + s) * NT + t] = a[s] * SCALE;
    }
  }
}

// ---------------- softmax over t (in place on d_out weights region) ----------------
__launch_bounds__(256)
__global__ void softmax_w(float* __restrict__ wbase)
{
  float* p = wbase + (size_t)blockIdx.x * NT;  // 64 rows
  __shared__ float r1[4], r2[4];
  __shared__ float bmax, bsum;
  const int tid = threadIdx.x, wv = tid >> 6, lane = tid & 63;

  float vals[8], mx = -1e30f;
#pragma unroll
  for (int i = 0; i < 8; ++i) {
    int t = tid + i * 256;
    vals[i] = (t < NT) ? p[t] : -1e30f;
    mx = fmaxf(mx, vals[i]);
  }
#pragma unroll
  for (int off = 32; off > 0; off >>= 1) mx = fmaxf(mx, __shfl_down(mx, off));
  if (lane == 0) r1[wv] = mx;
  __syncthreads();
  if (tid == 0) bmax = fmaxf(fmaxf(r1[0], r1[1]), fmaxf(r1[2], r1[3]));
  __syncthreads();
  mx = bmax;

  float sum = 0.f;
#pragma unroll
  for (int i = 0; i < 8; ++i) {
    int t = tid + i * 256;
    if (t < NT) { vals[i] = expf(vals[i] - mx); sum += vals[i]; }
  }
#pragma unroll
  for (int off = 32; off > 0; off >>= 1) sum += __shfl_down(sum, off);
  if (lane == 0) r2[wv] = sum;
  __syncthreads();
  if (tid == 0) bsum = r2[0] + r2[1] + r2[2] + r2[3];
  __syncthreads();
  const float inv = 1.f / bsum;
#pragma unroll
  for (int i = 0; i < 8; ++i) {
    int t = tid + i * 256;
    if (t < NT) p[t] = vals[i] * inv;
  }
}

// ---------------- attended = weights @ e_actions (two-stage) ----------------
__launch_bounds__(256)
__global__ void attended_partial(const float* __restrict__ outp, const float* __restrict__ wts,
                                 float* __restrict__ part)
{
  const int tid = threadIdx.x;
  const int e = blockIdx.x * 256 + tid;      // grid.x = 6
  const int b = blockIdx.y, z = blockIdx.z;  // 8, 4
  __shared__ float wl[8][256];
  float a[8];
#pragma unroll
  for (int s = 0; s < 8; ++s) a[s] = 0.f;

  const int tbeg = z * 512;
  const int tend = (tbeg + 512 < NT) ? tbeg + 512 : NT;
  for (int tb = tbeg; tb < tend; tb += 256) {
    const int cnt = (tend - tb < 256) ? (tend - tb) : 256;
    __syncthreads();
    for (int i = tid; i < 8 * 256; i += 256) {
      int s = i >> 8, tt = i & 255;
      wl[s][tt] = (tt < cnt) ? wts[(size_t)(b * N_B + s) * NT + tb + tt] : 0.f;
    }
    __syncthreads();
    for (int tt = 0; tt < cnt; ++tt) {
      float val = outp[((size_t)b * L_SEQ + 2 + tb + tt) * E_DIM + e];
#pragma unroll
      for (int s = 0; s < 8; ++s) a[s] += wl[s][tt] * val;
    }
  }
#pragma unroll
  for (int s = 0; s < 8; ++s)
    part[(((size_t)z * N_B + b) * N_B + s) * E_DIM + e] = a[s];
}
__global__ void attended_reduce(const float* __restrict__ part, float* __restrict__ outp)
{
  const int i = blockIdx.x * 256 + threadIdx.x;  // 8*8*1536 = 98304
  float s = 0.f;
#pragma unroll
  for (int z = 0; z < 4; ++z) s += part[(size_t)z * N_B * N_B * E_DIM + i];
  outp[i] = s;
}

// ---------------- host launcher ----------------
extern "C" void kernel_launch(void* const* d_in, const int* in_sizes, int n_in,
                              void* d_out, int out_size, void* d_ws, size_t ws_size,
                              hipStream_t stream)
{
  (void)in_sizes; (void)n_in; (void)out_size; (void)ws_size;
  const float* x     = (const float*)d_in[0];
  const float* Wv    = (const float*)d_in[1];
  const float* Wk    = (const float*)d_in[2];
  const float* Wq    = (const float*)d_in[3];
  const float* Wo    = (const float*)d_in[4];
  const float* bo    = (const float*)d_in[5];
  const float* gamma = (const float*)d_in[6];
  const float* beta  = (const float*)d_in[7];
  float* out = (float*)d_out;

  char* ws = (char*)d_ws;
  size_t off = 0;
  auto alloc = [&](size_t bytes) -> void* {
    void* p = ws + off;
    off += (bytes + 255) & ~(size_t)255;
    return p;
  };
  const size_t ME = (size_t)16384 * E_DIM;
  const size_t WE = (size_t)E_DIM * E_DIM;
  u16*   xb    = (u16*)alloc(ME * 2);
  u16*   wqb   = (u16*)alloc(WE * 2);
  u16*   wkb   = (u16*)alloc(WE * 2);
  u16*   wvb   = (u16*)alloc(WE * 2);
  u16*   wob   = (u16*)alloc(WE * 2);
  u16*   qb    = (u16*)alloc(ME * 2);
  u16*   kb    = (u16*)alloc(ME * 2);
  u16*   vb    = (u16*)alloc(ME * 2);
  u16*   aob   = (u16*)alloc(ME * 2);
  float* lnbuf = (float*)alloc(ME * 4);
  float* est   = (float*)alloc((size_t)N_B * E_DIM * 4);
  float* estp  = (float*)alloc((size_t)8 * N_B * E_DIM * 4);
  float* attp  = (float*)alloc((size_t)4 * N_B * N_B * E_DIM * 4);

  float* wout = out + 98304;  // weights region of d_out

  // allow 128 KB dynamic LDS (idempotent, host-side)
  hipFuncSetAttribute(reinterpret_cast<const void*>(gemml<0>),
                      hipFuncAttributeMaxDynamicSharedMemorySize, 131072);
  hipFuncSetAttribute(reinterpret_cast<const void*>(gemml<1>),
                      hipFuncAttributeMaxDynamicSharedMemorySize, 131072);

  // f32 -> bf16 conversions
  cvt_kernel<<<dim3((6291456 + 255) / 256), 256, 0, stream>>>(x, xb, 6291456);
  cvt_kernel<<<dim3((589824 + 255) / 256), 256, 0, stream>>>(Wq, wqb, 589824);
  cvt_kernel<<<dim3((589824 + 255) / 256), 256, 0, stream>>>(Wk, wkb, 589824);
  cvt_kernel<<<dim3((589824 + 255) / 256), 256, 0, stream>>>(Wv, wvb, 589824);
  cvt_kernel<<<dim3((589824 + 255) / 256), 256, 0, stream>>>(Wo, wob, 589824);

  // q/k/v projections (one launch, z-plane selects weight/output)
  gemml<0><<<dim3(6, 64, 3), 512, 131072, stream>>>(
      xb, wqb, wkb, wvb, qb, kb, vb, nullptr, nullptr, nullptr);

  // per-position 12x12 head-mix attention
  headmix<<<dim3(16384), 256, 0, stream>>>(qb, kb, vb, aob);

  // Wo projection + bias + residual (f32 out)
  gemml<1><<<dim3(6, 64, 1), 512, 131072, stream>>>(
      aob, wob, wob, wob, nullptr, nullptr, nullptr, lnbuf, bo, x);

  // in-place LayerNorm
  ln_kernel<<<dim3(16384), 256, 0, stream>>>(lnbuf, gamma, beta);

  // e_state = mean over L
  estate_partial<<<dim3(6, 8, 8), 256, 0, stream>>>(lnbuf, estp);
  estate_reduce<<<dim3(48), 256, 0, stream>>>(estp, est);

  // scores -> softmax (in place in d_out weights region)
  scores_kernel<<<dim3(32, 8), 256, 0, stream>>>(lnbuf, est, wout);
  softmax_w<<<dim3(64), 256, 0, stream>>>(wout);

  // attended
  attended_partial<<<dim3(6, 8, 4), 256, 0, stream>>>(lnbuf, wout, attp);
  attended_reduce<<<dim3(384), 256, 0, stream>>>(attp, out);
}

// Round 7
// 560.016 us; speedup vs baseline: 1.0467x; 1.0467x over previous
//
#include <hip/hip_runtime.h>
#include <stdint.h>

typedef unsigned short u16;
typedef __bf16 bf16_t;
typedef bf16_t bf16x8 __attribute__((ext_vector_type(8)));
typedef float f32x4 __attribute__((ext_vector_type(4)));

#define E_DIM 1536
#define N_B 8
#define L_SEQ 2048
#define NT 2046
#define SCALE 0.025515518f   // 1/sqrt(1536)
#define LN_EPS 1e-5f
#define NTILES 24            // K / 64

__device__ __forceinline__ u16 f2b(float f) {
  union { float f; uint32_t u; } v; v.f = f;
  uint32_t u = v.u + 0x7FFFu + ((v.u >> 16) & 1u);  // RNE
  return (u16)(u >> 16);
}
__device__ __forceinline__ float b2f(u16 h) {
  union { uint32_t u; float f; } v; v.u = ((uint32_t)h) << 16; return v.f;
}

// async global->LDS, 16B per lane; LDS dest = wave-uniform base + lane*16
__device__ __forceinline__ void gload16(const u16* g, const bf16_t* l) {
  __builtin_amdgcn_global_load_lds((const __attribute__((address_space(1))) void*)g,
                                   (__attribute__((address_space(3))) void*)l,
                                   16, 0, 0);
}

#define BAR()   __builtin_amdgcn_s_barrier()
#define SCHB()  __builtin_amdgcn_sched_barrier(0)
#define VM4()   asm volatile("s_waitcnt vmcnt(4)" ::: "memory")
#define VM0()   asm volatile("s_waitcnt vmcnt(0)" ::: "memory")

// ---------------- f32 -> bf16 conversion (vectorized) ----------------
__global__ void cvt_kernel(const float* __restrict__ in, u16* __restrict__ out, int nvec) {
  int i = blockIdx.x * 256 + threadIdx.x;
  if (i < nvec) {
    float4 f = ((const float4*)in)[i];
    ushort4 u;
    u.x = f2b(f.x); u.y = f2b(f.y); u.z = f2b(f.z); u.w = f2b(f.w);
    ((ushort4*)out)[i] = u;
  }
}

// ---------------- 256x256 register-pipelined bf16 GEMM (R3, best measured) ----
// C[i][j] = sum_k A[i][k]*B[j][k].  BM=BN=256, BK=64 (2 kk-halves of 32),
// 8 waves (2Mx4N), 512 thr, 128KB dyn LDS.  Per tile: 2 MFMA clusters of 32;
// fragment ds_reads for cluster c+1 issued BEFORE cluster c's MFMA.
// vmcnt ledger: see R3 notes (verified, 4 passing rounds of this family).
template<int FUSED>
__launch_bounds__(512, 2)
__global__ void gemm2c(const u16* __restrict__ Ag,
                       const u16* __restrict__ B0w, const u16* __restrict__ B1w,
                       const u16* __restrict__ B2w,
                       u16* __restrict__ C0, u16* __restrict__ C1, u16* __restrict__ C2,
                       float* __restrict__ Cf, const float* __restrict__ bias,
                       const float* __restrict__ resid)
{
  extern __shared__ __attribute__((aligned(16))) bf16_t lds[];

  // --- bijective XCD remap: 24-block groups (4 row-strips x 6 col-tiles)
  const int flat = (blockIdx.z * gridDim.y + blockIdx.y) * gridDim.x + blockIdx.x;
  const int xcd = flat & 7, bb_ = flat >> 3;
  const int gl = bb_ / 24, jj = bb_ % 24;
  const int g = gl * 8 + xcd;
  const int zz = g >> 4;
  const int gy = g & 15;
  const int tx = jj >> 2;
  const int ty = gy * 4 + (jj & 3);
  const int rowA = ty * 256, colB = tx * 256;

  const u16* Bg; u16* Cb;
  if (zz == 0)      { Bg = B0w; Cb = C0; }
  else if (zz == 1) { Bg = B1w; Cb = C1; }
  else              { Bg = B2w; Cb = C2; }

  const int tid = threadIdx.x;
  const int w = tid >> 6, lane = tid & 63;
  const int wr = w >> 2, wc = w & 3;

  // fragment read addressing (swizzled slot): row=64B, slot ^= (r>>1)&3
  const int rl = lane & 15, lsl = lane >> 4;
  const int sw8 = (lsl ^ ((rl >> 1) & 3)) * 8;
  const int arow = (wr * 128 + rl) * 32 + sw8;   // + m*512 + Aregion
  const int brow = (wc * 64 + rl) * 32 + sw8;    // + n*512 + Bregion

  // staging: chunk c = ld*512+tid; r=c>>2, sp=c&3; source pre-swizzled so the
  // linear LDS dest holds the swizzled layout (rule 21).
  const int r0s = tid >> 2, sps = tid & 3;
  const int sws = (sps ^ ((r0s >> 1) & 3)) * 8;
  const size_t sA0 = (size_t)(rowA + r0s) * E_DIM + sws;
  const size_t sA1 = (size_t)(rowA + 128 + r0s) * E_DIM + sws;
  const size_t sB0 = (size_t)(colB + r0s) * E_DIM + sws;
  const size_t sB1 = (size_t)(colB + 128 + r0s) * E_DIM + sws;
  const int wb0 = w * 512, wb1 = 4096 + w * 512;   // elem offsets in region

  // LDS regions (elem offsets): A (buf,kh) = (buf*2+kh)*8192; B = 32768 + same
  f32x4 acc[8][4];
#pragma unroll
  for (int m = 0; m < 8; ++m)
#pragma unroll
    for (int n = 0; n < 4; ++n)
#pragma unroll
      for (int q = 0; q < 4; ++q) acc[m][n][q] = 0.0f;

  // ---- prologue: stage t0.kh0(4), t0.kh1(4), t1.kh0(4) in FIFO groups
  gload16(Ag + sA0,      lds + 0     + wb0);  gload16(Ag + sA1,      lds + 0     + wb1);
  gload16(Bg + sB0,      lds + 32768 + wb0);  gload16(Bg + sB1,      lds + 32768 + wb1);
  gload16(Ag + sA0 + 32, lds + 8192  + wb0);  gload16(Ag + sA1 + 32, lds + 8192  + wb1);
  gload16(Bg + sB0 + 32, lds + 40960 + wb0);  gload16(Bg + sB1 + 32, lds + 40960 + wb1);
  gload16(Ag + sA0 + 64, lds + 16384 + wb0);  gload16(Ag + sA1 + 64, lds + 16384 + wb1);
  gload16(Bg + sB0 + 64, lds + 49152 + wb0);  gload16(Bg + sB1 + 64, lds + 49152 + wb1);
  VM4();                       // t0.kh0 + t0.kh1 landed; t1.kh0 outstanding
  BAR();

  bf16x8 a0[8], b0[4], a1[8], b1[4];
  // R0 = t0.kk0
#pragma unroll
  for (int m = 0; m < 8; ++m) a0[m] = *(const bf16x8*)&lds[0 + arow + m * 512];
#pragma unroll
  for (int n = 0; n < 4; ++n) b0[n] = *(const bf16x8*)&lds[32768 + brow + n * 512];

  for (int t = 0; t < NTILES; ++t) {
    const int cur = t & 1, nxt = cur ^ 1;
    const int Ak1 = (cur * 2 + 1) * 8192, Bk1 = 32768 + (cur * 2 + 1) * 8192;
    const int AkN0 = nxt * 2 * 8192,      BkN0 = 32768 + nxt * 2 * 8192;
    const int AkN1 = (nxt * 2 + 1) * 8192, BkN1 = 32768 + (nxt * 2 + 1) * 8192;

    // ---- issue R1 = cur.kk1 fragment reads; issue g12 = (t+1).kh1
#pragma unroll
    for (int m = 0; m < 8; ++m) a1[m] = *(const bf16x8*)&lds[Ak1 + arow + m * 512];
#pragma unroll
    for (int n = 0; n < 4; ++n) b1[n] = *(const bf16x8*)&lds[Bk1 + brow + n * 512];
    if (t + 1 < NTILES) {
      const size_t ko = (size_t)(t + 1) * 64 + 32;
      gload16(Ag + sA0 + ko, lds + AkN1 + wb0);  gload16(Ag + sA1 + ko, lds + AkN1 + wb1);
      gload16(Bg + sB0 + ko, lds + BkN1 + wb0);  gload16(Bg + sB1 + ko, lds + BkN1 + wb1);
    }
    SCHB();
    // ---- MFMA cluster 0 (kk0)
    __builtin_amdgcn_s_setprio(1);
#pragma unroll
    for (int m = 0; m < 8; ++m)
#pragma unroll
      for (int n = 0; n < 4; ++n)
        acc[m][n] = __builtin_amdgcn_mfma_f32_16x16x32_bf16(a0[m], b0[n], acc[m][n], 0, 0, 0);
    __builtin_amdgcn_s_setprio(0);
    SCHB();
    if (t + 1 < NTILES) { VM4(); }   // retire (t+1).kh0
    BAR();

    // ---- issue g34 = (t+2).kh0 -> cur.kh0 (readers retired); R0' = (t+1).kk0
    if (t + 2 < NTILES) {
      const size_t ko = (size_t)(t + 2) * 64;
      gload16(Ag + sA0 + ko, lds + cur * 2 * 8192 + wb0);
      gload16(Ag + sA1 + ko, lds + cur * 2 * 8192 + wb1);
      gload16(Bg + sB0 + ko, lds + 32768 + cur * 2 * 8192 + wb0);
      gload16(Bg + sB1 + ko, lds + 32768 + cur * 2 * 8192 + wb1);
    }
    if (t + 1 < NTILES) {
#pragma unroll
      for (int m = 0; m < 8; ++m) a0[m] = *(const bf16x8*)&lds[AkN0 + arow + m * 512];
#pragma unroll
      for (int n = 0; n < 4; ++n) b0[n] = *(const bf16x8*)&lds[BkN0 + brow + n * 512];
    }
    SCHB();
    // ---- MFMA cluster 1 (kk1)
    __builtin_amdgcn_s_setprio(1);
#pragma unroll
    for (int m = 0; m < 8; ++m)
#pragma unroll
      for (int n = 0; n < 4; ++n)
        acc[m][n] = __builtin_amdgcn_mfma_f32_16x16x32_bf16(a1[m], b1[n], acc[m][n], 0, 0, 0);
    __builtin_amdgcn_s_setprio(0);
    SCHB();
    if (t + 2 < NTILES)      { VM4(); }
    else if (t + 1 < NTILES) { VM0(); }
    BAR();
  }

  // ---- epilogue: C/D layout col=lane&15, row=(lane>>4)*4+reg [m89]
  const int r0 = (lane >> 4) * 4;
#pragma unroll
  for (int m = 0; m < 8; ++m) {
#pragma unroll
    for (int n = 0; n < 4; ++n) {
      const int gcol = colB + wc * 64 + n * 16 + rl;
#pragma unroll
      for (int q = 0; q < 4; ++q) {
        const int grow = rowA + wr * 128 + m * 16 + r0 + q;
        const size_t idx = (size_t)grow * E_DIM + gcol;
        if (FUSED) Cf[idx] = acc[m][n][q] + bias[gcol] + resid[idx];
        else       Cb[idx] = f2b(acc[m][n][q]);
      }
    }
  }
}

// ---------------- per-position 12x12 head-mix attention ----------------
__launch_bounds__(256)
__global__ void headmix(const u16* __restrict__ qb, const u16* __restrict__ kb,
                        const u16* __restrict__ vb, u16* __restrict__ aob)
{
  __shared__ float qs[12 * 132], ks2[12 * 132], vs[12 * 132];
  __shared__ float att[12][12];
  const int tid = threadIdx.x;
  const size_t base = (size_t)blockIdx.x * E_DIM;

  for (int e = tid; e < E_DIM; e += 256) {
    int i = e >> 7, d = e & 127, p = i * 132 + d;
    qs[p]  = b2f(qb[base + e]);
    ks2[p] = b2f(kb[base + e]);
    vs[p]  = b2f(vb[base + e]);
  }
  __syncthreads();

  if (tid < 144) {
    int i = tid / 12, j = tid % 12;
    float s = 0.f;
#pragma unroll 8
    for (int d = 0; d < 128; ++d) s += qs[i * 132 + d] * ks2[j * 132 + d];
    att[i][j] = s * SCALE;
  }
  __syncthreads();

  if (tid < 12) {
    float mx = att[tid][0];
#pragma unroll
    for (int j = 1; j < 12; ++j) mx = fmaxf(mx, att[tid][j]);
    float ev[12], sum = 0.f;
#pragma unroll
    for (int j = 0; j < 12; ++j) { ev[j] = expf(att[tid][j] - mx); sum += ev[j]; }
    float inv = 1.f / sum;
#pragma unroll
    for (int j = 0; j < 12; ++j) att[tid][j] = ev[j] * inv;
  }
  __syncthreads();

  for (int e = tid; e < E_DIM; e += 256) {
    int i = e >> 7, d = e & 127;
    float o = 0.f;
#pragma unroll
    for (int j = 0; j < 12; ++j) o += att[i][j] * vs[j * 132 + d];
    aob[base + e] = f2b(o);
  }
}

// ---------------- LayerNorm: f32 in -> bf16 out (stage C reads bf16) ----------------
__launch_bounds__(256)
__global__ void ln_kernel(const float* __restrict__ p, u16* __restrict__ ho,
                          const float* __restrict__ gamma, const float* __restrict__ beta)
{
  __shared__ float rs[4], rq[4];
  __shared__ float mean_s, rstd_s;
  const int tid = threadIdx.x, w = tid >> 6, lane = tid & 63;
  const float* row = p + (size_t)blockIdx.x * E_DIM;
  u16* orow = ho + (size_t)blockIdx.x * E_DIM;

  float v[6], s = 0.f, sq = 0.f;
#pragma unroll
  for (int i = 0; i < 6; ++i) {
    v[i] = row[tid + i * 256];
    s += v[i]; sq += v[i] * v[i];
  }
#pragma unroll
  for (int off = 32; off > 0; off >>= 1) {
    s  += __shfl_down(s, off);
    sq += __shfl_down(sq, off);
  }
  if (lane == 0) { rs[w] = s; rq[w] = sq; }
  __syncthreads();
  if (tid == 0) {
    float S = rs[0] + rs[1] + rs[2] + rs[3];
    float Q = rq[0] + rq[1] + rq[2] + rq[3];
    float mu = S * (1.f / 1536.f);
    float var = Q * (1.f / 1536.f) - mu * mu;
    mean_s = mu; rstd_s = rsqrtf(var + LN_EPS);
  }
  __syncthreads();
  const float mu = mean_s, rstd = rstd_s;
#pragma unroll
  for (int i = 0; i < 6; ++i) {
    int e = tid + i * 256;
    orow[e] = f2b((v[i] - mu) * rstd * gamma[e] + beta[e]);
  }
}

// ---------------- e_state = mean over L (two-stage, deterministic) ----------------
__global__ void estate_partial(const u16* __restrict__ outp, float* __restrict__ part)
{
  const int e = blockIdx.x * 256 + threadIdx.x;  // grid.x = 6
  const int b = blockIdx.y, z = blockIdx.z;      // 8, 8
  const u16* p = outp + ((size_t)b * L_SEQ + z * 256) * E_DIM + e;
  float acc = 0.f;
  for (int l = 0; l < 256; ++l) acc += b2f(p[(size_t)l * E_DIM]);
  part[(size_t)(z * N_B + b) * E_DIM + e] = acc;
}
__global__ void estate_reduce(const float* __restrict__ part, float* __restrict__ est)
{
  const int i = blockIdx.x * 256 + threadIdx.x;  // 8*1536 = 12288
  if (i < N_B * E_DIM) {
    float s = 0.f;
#pragma unroll
    for (int z = 0; z < 8; ++z) s += part[(size_t)z * N_B * E_DIM + i];
    est[i] = s * (1.f / 2048.f);
  }
}

// ---------------- scores[b][s][t] = dot(e_state[s], out[b][2+t]) * SCALE ----------
__launch_bounds__(256)
__global__ void scores_kernel(const u16* __restrict__ outp, const float* __restrict__ est,
                              float* __restrict__ wout)
{
  __shared__ float es[N_B * E_DIM];  // 48 KB
  const int tid = threadIdx.x, wv = tid >> 6, lane = tid & 63;
  const int b = blockIdx.y;
  for (int i = tid; i < N_B * E_DIM; i += 256) es[i] = est[i];
  __syncthreads();

  for (int ti = 0; ti < 16; ++ti) {
    int t = blockIdx.x * 64 + wv * 16 + ti;   // wave-uniform
    if (t >= NT) continue;
    const uint32_t* row =
        (const uint32_t*)(outp + ((size_t)b * L_SEQ + 2 + t) * E_DIM);
    float a[8];
#pragma unroll
    for (int s = 0; s < 8; ++s) a[s] = 0.f;
    for (int c = 0; c < 12; ++c) {
      uint32_t pv = row[c * 64 + lane];
      float v0 = b2f((u16)(pv & 0xFFFF)), v1 = b2f((u16)(pv >> 16));
      int idx = (c * 64 + lane) * 2;
#pragma unroll
      for (int s = 0; s < 8; ++s)
        a[s] += es[s * E_DIM + idx] * v0 + es[s * E_DIM + idx + 1] * v1;
    }
#pragma unroll
    for (int off = 32; off > 0; off >>= 1)
#pragma unroll
      for (int s = 0; s < 8; ++s) a[s] += __shfl_down(a[s], off);
    if (lane == 0) {
#pragma unroll
      for (int s = 0; s < 8; ++s)
        wout[(size_t)(b * N_B + s) * NT + t] = a[s] * SCALE;
    }
  }
}

// ---------------- softmax over t (in place on d_out weights region) ----------------
__launch_bounds__(256)
__global__ void softmax_w(float* __restrict__ wbase)
{
  float* p = wbase + (size_t)blockIdx.x * NT;  // 64 rows
  __shared__ float r1[4], r2[4];
  __shared__ float bmax, bsum;
  const int tid = threadIdx.x, wv = tid >> 6, lane = tid & 63;

  float vals[8], mx = -1e30f;
#pragma unroll
  for (int i = 0; i < 8; ++i) {
    int t = tid + i * 256;
    vals[i] = (t < NT) ? p[t] : -1e30f;
    mx = fmaxf(mx, vals[i]);
  }
#pragma unroll
  for (int off = 32; off > 0; off >>= 1) mx = fmaxf(mx, __shfl_down(mx, off));
  if (lane == 0) r1[wv] = mx;
  __syncthreads();
  if (tid == 0) bmax = fmaxf(fmaxf(r1[0], r1[1]), fmaxf(r1[2], r1[3]));
  __syncthreads();
  mx = bmax;

  float sum = 0.f;
#pragma unroll
  for (int i = 0; i < 8; ++i) {
    int t = tid + i * 256;
    if (t < NT) { vals[i] = expf(vals[i] - mx); sum += vals[i]; }
  }
#pragma unroll
  for (int off = 32; off > 0; off >>= 1) sum += __shfl_down(sum, off);
  if (lane == 0) r2[wv] = sum;
  __syncthreads();
  if (tid == 0) bsum = r2[0] + r2[1] + r2[2] + r2[3];
  __syncthreads();
  const float inv = 1.f / bsum;
#pragma unroll
  for (int i = 0; i < 8; ++i) {
    int t = tid + i * 256;
    if (t < NT) p[t] = vals[i] * inv;
  }
}

// ---------------- attended = weights @ e_actions (two-stage) ----------------
__launch_bounds__(256)
__global__ void attended_partial(const u16* __restrict__ outp, const float* __restrict__ wts,
                                 float* __restrict__ part)
{
  const int tid = threadIdx.x;
  const int e = blockIdx.x * 256 + tid;      // grid.x = 6
  const int b = blockIdx.y, z = blockIdx.z;  // 8, 4
  __shared__ float wl[8][256];
  float a[8];
#pragma unroll
  for (int s = 0; s < 8; ++s) a[s] = 0.f;

  const int tbeg = z * 512;
  const int tend = (tbeg + 512 < NT) ? tbeg + 512 : NT;
  for (int tb = tbeg; tb < tend; tb += 256) {
    const int cnt = (tend - tb < 256) ? (tend - tb) : 256;
    __syncthreads();
    for (int i = tid; i < 8 * 256; i += 256) {
      int s = i >> 8, tt = i & 255;
      wl[s][tt] = (tt < cnt) ? wts[(size_t)(b * N_B + s) * NT + tb + tt] : 0.f;
    }
    __syncthreads();
    for (int tt = 0; tt < cnt; ++tt) {
      float val = b2f(outp[((size_t)b * L_SEQ + 2 + tb + tt) * E_DIM + e]);
#pragma unroll
      for (int s = 0; s < 8; ++s) a[s] += wl[s][tt] * val;
    }
  }
#pragma unroll
  for (int s = 0; s < 8; ++s)
    part[(((size_t)z * N_B + b) * N_B + s) * E_DIM + e] = a[s];
}
__global__ void attended_reduce(const float* __restrict__ part, float* __restrict__ outp)
{
  const int i = blockIdx.x * 256 + threadIdx.x;  // 8*8*1536 = 98304
  float s = 0.f;
#pragma unroll
  for (int z = 0; z < 4; ++z) s += part[(size_t)z * N_B * N_B * E_DIM + i];
  outp[i] = s;
}

// ---------------- host launcher ----------------
extern "C" void kernel_launch(void* const* d_in, const int* in_sizes, int n_in,
                              void* d_out, int out_size, void* d_ws, size_t ws_size,
                              hipStream_t stream)
{
  (void)in_sizes; (void)n_in; (void)out_size; (void)ws_size;
  const float* x     = (const float*)d_in[0];
  const float* Wv    = (const float*)d_in[1];
  const float* Wk    = (const float*)d_in[2];
  const float* Wq    = (const float*)d_in[3];
  const float* Wo    = (const float*)d_in[4];
  const float* bo    = (const float*)d_in[5];
  const float* gamma = (const float*)d_in[6];
  const float* beta  = (const float*)d_in[7];
  float* out = (float*)d_out;

  char* ws = (char*)d_ws;
  size_t off = 0;
  auto alloc = [&](size_t bytes) -> void* {
    void* p = ws + off;
    off += (bytes + 255) & ~(size_t)255;
    return p;
  };
  const size_t ME = (size_t)16384 * E_DIM;
  const size_t WE = (size_t)E_DIM * E_DIM;
  u16*   xb    = (u16*)alloc(ME * 2);
  u16*   wqb   = (u16*)alloc(WE * 2);
  u16*   wkb   = (u16*)alloc(WE * 2);
  u16*   wvb   = (u16*)alloc(WE * 2);
  u16*   wob   = (u16*)alloc(WE * 2);
  u16*   qb    = (u16*)alloc(ME * 2);
  u16*   kb    = (u16*)alloc(ME * 2);
  u16*   vb    = (u16*)alloc(ME * 2);
  u16*   aob   = (u16*)alloc(ME * 2);   // headmix out; REUSED as bf16 LN out
  float* lnbuf = (float*)alloc(ME * 4);
  float* est   = (float*)alloc((size_t)N_B * E_DIM * 4);
  float* estp  = (float*)alloc((size_t)8 * N_B * E_DIM * 4);
  float* attp  = (float*)alloc((size_t)4 * N_B * N_B * E_DIM * 4);
  // footprint identical to R5 (known to fit ws_size) — no new buffers.

  float* wout = out + 98304;  // weights region of d_out

  // allow 128 KB dynamic LDS (idempotent, host-side)
  hipFuncSetAttribute(reinterpret_cast<const void*>(gemm2c<0>),
                      hipFuncAttributeMaxDynamicSharedMemorySize, 131072);
  hipFuncSetAttribute(reinterpret_cast<const void*>(gemm2c<1>),
                      hipFuncAttributeMaxDynamicSharedMemorySize, 131072);

  // f32 -> bf16 conversions
  cvt_kernel<<<dim3((6291456 + 255) / 256), 256, 0, stream>>>(x, xb, 6291456);
  cvt_kernel<<<dim3((589824 + 255) / 256), 256, 0, stream>>>(Wq, wqb, 589824);
  cvt_kernel<<<dim3((589824 + 255) / 256), 256, 0, stream>>>(Wk, wkb, 589824);
  cvt_kernel<<<dim3((589824 + 255) / 256), 256, 0, stream>>>(Wv, wvb, 589824);
  cvt_kernel<<<dim3((589824 + 255) / 256), 256, 0, stream>>>(Wo, wob, 589824);

  // q/k/v projections (one launch, z-plane selects weight/output)
  gemm2c<0><<<dim3(6, 64, 3), 512, 131072, stream>>>(
      xb, wqb, wkb, wvb, qb, kb, vb, nullptr, nullptr, nullptr);

  // per-position 12x12 head-mix attention
  headmix<<<dim3(16384), 256, 0, stream>>>(qb, kb, vb, aob);

  // Wo projection + bias + residual (f32 out)
  gemm2c<1><<<dim3(6, 64, 1), 512, 131072, stream>>>(
      aob, wob, wob, wob, nullptr, nullptr, nullptr, lnbuf, bo, x);

  // LayerNorm: f32 -> bf16, written into aob (dead after gemm2c<1>;
  // rewritten by headmix on every replay -> deterministic)
  u16* lnh = aob;
  ln_kernel<<<dim3(16384), 256, 0, stream>>>(lnbuf, lnh, gamma, beta);

  // e_state = mean over L (bf16 reads)
  estate_partial<<<dim3(6, 8, 8), 256, 0, stream>>>(lnh, estp);
  estate_reduce<<<dim3(48), 256, 0, stream>>>(estp, est);

  // scores -> softmax (in place in d_out weights region)
  scores_kernel<<<dim3(32, 8), 256, 0, stream>>>(lnh, est, wout);
  softmax_w<<<dim3(64), 256, 0, stream>>>(wout);

  // attended
  attended_partial<<<dim3(6, 8, 4), 256, 0, stream>>>(lnh, wout, attp);
  attended_reduce<<<dim3(384), 256, 0, stream>>>(attp, out);
}

// Round 8
// 528.511 us; speedup vs baseline: 1.1091x; 1.0596x over previous
//
#include <hip/hip_runtime.h>
#include <stdint.h>

typedef unsigned short u16;
typedef __bf16 bf16_t;
typedef bf16_t bf16x8 __attribute__((ext_vector_type(8)));
typedef float f32x4 __attribute__((ext_vector_type(4)));

#define E_DIM 1536
#define N_B 8
#define L_SEQ 2048
#define NT 2046
#define SCALE 0.025515518f   // 1/sqrt(1536)
#define LN_EPS 1e-5f
#define NTILES 24            // K / 64
#define NXV 6291456          // x float4 count
#define NWV 589824           // one weight float4 count

__device__ __forceinline__ u16 f2b(float f) {
  union { float f; uint32_t u; } v; v.f = f;
  uint32_t u = v.u + 0x7FFFu + ((v.u >> 16) & 1u);  // RNE
  return (u16)(u >> 16);
}
__device__ __forceinline__ float b2f(u16 h) {
  union { uint32_t u; float f; } v; v.u = ((uint32_t)h) << 16; return v.f;
}

// async global->LDS, 16B per lane; LDS dest = wave-uniform base + lane*16
__device__ __forceinline__ void gload16(const u16* g, const bf16_t* l) {
  __builtin_amdgcn_global_load_lds((const __attribute__((address_space(1))) void*)g,
                                   (__attribute__((address_space(3))) void*)l,
                                   16, 0, 0);
}

#define BAR()   __builtin_amdgcn_s_barrier()
#define SCHB()  __builtin_amdgcn_sched_barrier(0)
#define VM4()   asm volatile("s_waitcnt vmcnt(4)" ::: "memory")
#define VM0()   asm volatile("s_waitcnt vmcnt(0)" ::: "memory")

// ---------------- fused f32 -> bf16 conversion (x + 4 weights, 1 launch) ------
__global__ void cvt_all(const float* __restrict__ x,  const float* __restrict__ Wq,
                        const float* __restrict__ Wk, const float* __restrict__ Wv,
                        const float* __restrict__ Wo,
                        u16* __restrict__ xb,  u16* __restrict__ wqb,
                        u16* __restrict__ wkb, u16* __restrict__ wvb,
                        u16* __restrict__ wob)
{
  int i = blockIdx.x * 256 + threadIdx.x;   // float4 index, grid covers exactly
  const float* src; u16* dst; int o;
  if (i < NXV)              { src = x;  dst = xb;  o = i; }
  else if (i < NXV + NWV)   { src = Wq; dst = wqb; o = i - NXV; }
  else if (i < NXV + 2*NWV) { src = Wk; dst = wkb; o = i - NXV - NWV; }
  else if (i < NXV + 3*NWV) { src = Wv; dst = wvb; o = i - NXV - 2*NWV; }
  else                      { src = Wo; dst = wob; o = i - NXV - 3*NWV; }
  float4 f = ((const float4*)src)[o];
  ushort4 u;
  u.x = f2b(f.x); u.y = f2b(f.y); u.z = f2b(f.z); u.w = f2b(f.w);
  ((ushort4*)dst)[o] = u;
}

// ---------------- 256x256 register-pipelined bf16 GEMM (R3 schedule) ----------
// FUSED=0: C = bf16(acc)  (QKV; z selects B/C)
// FUSED=2: C = bf16(acc + bias[col] + b2f(resid16[idx]))  (Wo, pre-LN bf16 out)
template<int FUSED>
__launch_bounds__(512, 2)
__global__ void gemm2c(const u16* __restrict__ Ag,
                       const u16* __restrict__ B0w, const u16* __restrict__ B1w,
                       const u16* __restrict__ B2w,
                       u16* __restrict__ C0, u16* __restrict__ C1, u16* __restrict__ C2,
                       const float* __restrict__ bias, const u16* __restrict__ resid16)
{
  extern __shared__ __attribute__((aligned(16))) bf16_t lds[];

  // --- bijective XCD remap: 24-block groups (4 row-strips x 6 col-tiles)
  const int flat = (blockIdx.z * gridDim.y + blockIdx.y) * gridDim.x + blockIdx.x;
  const int xcd = flat & 7, bb_ = flat >> 3;
  const int gl = bb_ / 24, jj = bb_ % 24;
  const int g = gl * 8 + xcd;
  const int zz = g >> 4;
  const int gy = g & 15;
  const int tx = jj >> 2;
  const int ty = gy * 4 + (jj & 3);
  const int rowA = ty * 256, colB = tx * 256;

  const u16* Bg; u16* Cb;
  if (zz == 0)      { Bg = B0w; Cb = C0; }
  else if (zz == 1) { Bg = B1w; Cb = C1; }
  else              { Bg = B2w; Cb = C2; }

  const int tid = threadIdx.x;
  const int w = tid >> 6, lane = tid & 63;
  const int wr = w >> 2, wc = w & 3;

  // fragment read addressing (swizzled slot): row=64B, slot ^= (r>>1)&3
  const int rl = lane & 15, lsl = lane >> 4;
  const int sw8 = (lsl ^ ((rl >> 1) & 3)) * 8;
  const int arow = (wr * 128 + rl) * 32 + sw8;   // + m*512 + Aregion
  const int brow = (wc * 64 + rl) * 32 + sw8;    // + n*512 + Bregion

  // staging: chunk c = ld*512+tid; r=c>>2, sp=c&3; source pre-swizzled so the
  // linear LDS dest holds the swizzled layout (rule 21).
  const int r0s = tid >> 2, sps = tid & 3;
  const int sws = (sps ^ ((r0s >> 1) & 3)) * 8;
  const size_t sA0 = (size_t)(rowA + r0s) * E_DIM + sws;
  const size_t sA1 = (size_t)(rowA + 128 + r0s) * E_DIM + sws;
  const size_t sB0 = (size_t)(colB + r0s) * E_DIM + sws;
  const size_t sB1 = (size_t)(colB + 128 + r0s) * E_DIM + sws;
  const int wb0 = w * 512, wb1 = 4096 + w * 512;   // elem offsets in region

  // LDS regions (elem offsets): A (buf,kh) = (buf*2+kh)*8192; B = 32768 + same
  f32x4 acc[8][4];
#pragma unroll
  for (int m = 0; m < 8; ++m)
#pragma unroll
    for (int n = 0; n < 4; ++n)
#pragma unroll
      for (int q = 0; q < 4; ++q) acc[m][n][q] = 0.0f;

  // ---- prologue: stage t0.kh0(4), t0.kh1(4), t1.kh0(4) in FIFO groups
  gload16(Ag + sA0,      lds + 0     + wb0);  gload16(Ag + sA1,      lds + 0     + wb1);
  gload16(Bg + sB0,      lds + 32768 + wb0);  gload16(Bg + sB1,      lds + 32768 + wb1);
  gload16(Ag + sA0 + 32, lds + 8192  + wb0);  gload16(Ag + sA1 + 32, lds + 8192  + wb1);
  gload16(Bg + sB0 + 32, lds + 40960 + wb0);  gload16(Bg + sB1 + 32, lds + 40960 + wb1);
  gload16(Ag + sA0 + 64, lds + 16384 + wb0);  gload16(Ag + sA1 + 64, lds + 16384 + wb1);
  gload16(Bg + sB0 + 64, lds + 49152 + wb0);  gload16(Bg + sB1 + 64, lds + 49152 + wb1);
  VM4();                       // t0.kh0 + t0.kh1 landed; t1.kh0 outstanding
  BAR();

  bf16x8 a0[8], b0[4], a1[8], b1[4];
  // R0 = t0.kk0
#pragma unroll
  for (int m = 0; m < 8; ++m) a0[m] = *(const bf16x8*)&lds[0 + arow + m * 512];
#pragma unroll
  for (int n = 0; n < 4; ++n) b0[n] = *(const bf16x8*)&lds[32768 + brow + n * 512];

  for (int t = 0; t < NTILES; ++t) {
    const int cur = t & 1, nxt = cur ^ 1;
    const int Ak1 = (cur * 2 + 1) * 8192, Bk1 = 32768 + (cur * 2 + 1) * 8192;
    const int AkN0 = nxt * 2 * 8192,      BkN0 = 32768 + nxt * 2 * 8192;
    const int AkN1 = (nxt * 2 + 1) * 8192, BkN1 = 32768 + (nxt * 2 + 1) * 8192;

    // ---- issue R1 = cur.kk1 fragment reads; issue g12 = (t+1).kh1
#pragma unroll
    for (int m = 0; m < 8; ++m) a1[m] = *(const bf16x8*)&lds[Ak1 + arow + m * 512];
#pragma unroll
    for (int n = 0; n < 4; ++n) b1[n] = *(const bf16x8*)&lds[Bk1 + brow + n * 512];
    if (t + 1 < NTILES) {
      const size_t ko = (size_t)(t + 1) * 64 + 32;
      gload16(Ag + sA0 + ko, lds + AkN1 + wb0);  gload16(Ag + sA1 + ko, lds + AkN1 + wb1);
      gload16(Bg + sB0 + ko, lds + BkN1 + wb0);  gload16(Bg + sB1 + ko, lds + BkN1 + wb1);
    }
    SCHB();
    // ---- MFMA cluster 0 (kk0)
    __builtin_amdgcn_s_setprio(1);
#pragma unroll
    for (int m = 0; m < 8; ++m)
#pragma unroll
      for (int n = 0; n < 4; ++n)
        acc[m][n] = __builtin_amdgcn_mfma_f32_16x16x32_bf16(a0[m], b0[n], acc[m][n], 0, 0, 0);
    __builtin_amdgcn_s_setprio(0);
    SCHB();
    if (t + 1 < NTILES) { VM4(); }   // retire (t+1).kh0
    BAR();

    // ---- issue g34 = (t+2).kh0 -> cur.kh0 (readers retired); R0' = (t+1).kk0
    if (t + 2 < NTILES) {
      const size_t ko = (size_t)(t + 2) * 64;
      gload16(Ag + sA0 + ko, lds + cur * 2 * 8192 + wb0);
      gload16(Ag + sA1 + ko, lds + cur * 2 * 8192 + wb1);
      gload16(Bg + sB0 + ko, lds + 32768 + cur * 2 * 8192 + wb0);
      gload16(Bg + sB1 + ko, lds + 32768 + cur * 2 * 8192 + wb1);
    }
    if (t + 1 < NTILES) {
#pragma unroll
      for (int m = 0; m < 8; ++m) a0[m] = *(const bf16x8*)&lds[AkN0 + arow + m * 512];
#pragma unroll
      for (int n = 0; n < 4; ++n) b0[n] = *(const bf16x8*)&lds[BkN0 + brow + n * 512];
    }
    SCHB();
    // ---- MFMA cluster 1 (kk1)
    __builtin_amdgcn_s_setprio(1);
#pragma unroll
    for (int m = 0; m < 8; ++m)
#pragma unroll
      for (int n = 0; n < 4; ++n)
        acc[m][n] = __builtin_amdgcn_mfma_f32_16x16x32_bf16(a1[m], b1[n], acc[m][n], 0, 0, 0);
    __builtin_amdgcn_s_setprio(0);
    SCHB();
    if (t + 2 < NTILES)      { VM4(); }
    else if (t + 1 < NTILES) { VM0(); }
    BAR();
  }

  // ---- epilogue: C/D layout col=lane&15, row=(lane>>4)*4+reg [m89]
  const int r0 = (lane >> 4) * 4;
#pragma unroll
  for (int m = 0; m < 8; ++m) {
#pragma unroll
    for (int n = 0; n < 4; ++n) {
      const int gcol = colB + wc * 64 + n * 16 + rl;
#pragma unroll
      for (int q = 0; q < 4; ++q) {
        const int grow = rowA + wr * 128 + m * 16 + r0 + q;
        const size_t idx = (size_t)grow * E_DIM + gcol;
        if (FUSED == 2)
          Cb[idx] = f2b(acc[m][n][q] + bias[gcol] + b2f(resid16[idx]));
        else
          Cb[idx] = f2b(acc[m][n][q]);
      }
    }
  }
}

// ---------------- per-position 12x12 head-mix attention (vectorized) ----------
__launch_bounds__(256)
__global__ void headmix(const u16* __restrict__ qb, const u16* __restrict__ kb,
                        const u16* __restrict__ vb, u16* __restrict__ aob)
{
  __shared__ float qs[12 * 132], ks2[12 * 132], vs[12 * 132];
  __shared__ float att[12][12];
  const int tid = threadIdx.x;
  const size_t base = (size_t)blockIdx.x * E_DIM;

  if (tid < 192) {   // 192 threads x 8 bf16 (16B) per array
    const int i = tid >> 4, d0 = (tid & 15) * 8, p = i * 132 + d0;
    uint4 q4 = *(const uint4*)(qb + base + tid * 8);
    uint4 k4 = *(const uint4*)(kb + base + tid * 8);
    uint4 v4 = *(const uint4*)(vb + base + tid * 8);
#pragma unroll
    for (int c = 0; c < 4; ++c) {
      uint32_t qa = (&q4.x)[c], ka = (&k4.x)[c], va = (&v4.x)[c];
      qs[p + 2*c]     = b2f((u16)(qa & 0xFFFF));
      qs[p + 2*c + 1] = b2f((u16)(qa >> 16));
      ks2[p + 2*c]     = b2f((u16)(ka & 0xFFFF));
      ks2[p + 2*c + 1] = b2f((u16)(ka >> 16));
      vs[p + 2*c]     = b2f((u16)(va & 0xFFFF));
      vs[p + 2*c + 1] = b2f((u16)(va >> 16));
    }
  }
  __syncthreads();

  if (tid < 144) {
    int i = tid / 12, j = tid % 12;
    const float4* qr = (const float4*)&qs[i * 132];
    const float4* kr = (const float4*)&ks2[j * 132];
    float s = 0.f;
#pragma unroll 8
    for (int d4 = 0; d4 < 32; ++d4) {
      float4 a = qr[d4], b = kr[d4];
      s += a.x * b.x + a.y * b.y + a.z * b.z + a.w * b.w;
    }
    att[i][j] = s * SCALE;
  }
  __syncthreads();

  if (tid < 12) {
    float mx = att[tid][0];
#pragma unroll
    for (int j = 1; j < 12; ++j) mx = fmaxf(mx, att[tid][j]);
    float ev[12], sum = 0.f;
#pragma unroll
    for (int j = 0; j < 12; ++j) { ev[j] = expf(att[tid][j] - mx); sum += ev[j]; }
    float inv = 1.f / sum;
#pragma unroll
    for (int j = 0; j < 12; ++j) att[tid][j] = ev[j] * inv;
  }
  __syncthreads();

  for (int e = tid; e < E_DIM; e += 256) {
    int i = e >> 7, d = e & 127;
    float o = 0.f;
#pragma unroll
    for (int j = 0; j < 12; ++j) o += att[i][j] * vs[j * 132 + d];
    aob[base + e] = f2b(o);
  }
}

// ---------------- LayerNorm: bf16 in -> bf16 out (u32-packed) ----------------
__launch_bounds__(256)
__global__ void ln_kernel(const u16* __restrict__ p, u16* __restrict__ ho,
                          const float* __restrict__ gamma, const float* __restrict__ beta)
{
  __shared__ float rs[4], rq[4];
  __shared__ float mean_s, rstd_s;
  const int tid = threadIdx.x, w = tid >> 6, lane = tid & 63;
  const uint32_t* row = (const uint32_t*)(p + (size_t)blockIdx.x * E_DIM);   // 768 u32
  uint32_t* orow = (uint32_t*)(ho + (size_t)blockIdx.x * E_DIM);

  float v[6], s = 0.f, sq = 0.f;
#pragma unroll
  for (int i = 0; i < 3; ++i) {
    uint32_t u = row[tid + i * 256];
    float lo = b2f((u16)(u & 0xFFFF)), hi = b2f((u16)(u >> 16));
    v[2*i] = lo; v[2*i+1] = hi;
    s += lo + hi; sq += lo * lo + hi * hi;
  }
#pragma unroll
  for (int off = 32; off > 0; off >>= 1) {
    s  += __shfl_down(s, off);
    sq += __shfl_down(sq, off);
  }
  if (lane == 0) { rs[w] = s; rq[w] = sq; }
  __syncthreads();
  if (tid == 0) {
    float S = rs[0] + rs[1] + rs[2] + rs[3];
    float Q = rq[0] + rq[1] + rq[2] + rq[3];
    float mu = S * (1.f / 1536.f);
    float var = Q * (1.f / 1536.f) - mu * mu;
    mean_s = mu; rstd_s = rsqrtf(var + LN_EPS);
  }
  __syncthreads();
  const float mu = mean_s, rstd = rstd_s;
#pragma unroll
  for (int i = 0; i < 3; ++i) {
    int j = tid + i * 256;              // u32 index; elements 2j, 2j+1
    float o0 = (v[2*i]   - mu) * rstd * gamma[2*j]   + beta[2*j];
    float o1 = (v[2*i+1] - mu) * rstd * gamma[2*j+1] + beta[2*j+1];
    orow[j] = (uint32_t)f2b(o0) | ((uint32_t)f2b(o1) << 16);
  }
}

// ---------------- e_state = mean over L (two-stage, deterministic) ----------------
__global__ void estate_partial(const u16* __restrict__ outp, float* __restrict__ part)
{
  const int e = blockIdx.x * 256 + threadIdx.x;  // grid.x = 6
  const int b = blockIdx.y, z = blockIdx.z;      // 8, 8
  const u16* p = outp + ((size_t)b * L_SEQ + z * 256) * E_DIM + e;
  float acc = 0.f;
  for (int l = 0; l < 256; ++l) acc += b2f(p[(size_t)l * E_DIM]);
  part[(size_t)(z * N_B + b) * E_DIM + e] = acc;
}
__global__ void estate_reduce(const float* __restrict__ part, float* __restrict__ est)
{
  const int i = blockIdx.x * 256 + threadIdx.x;  // 8*1536 = 12288
  if (i < N_B * E_DIM) {
    float s = 0.f;
#pragma unroll
    for (int z = 0; z < 8; ++z) s += part[(size_t)z * N_B * E_DIM + i];
    est[i] = s * (1.f / 2048.f);
  }
}

// ---------------- scores[b][s][t] = dot(e_state[s], out[b][2+t]) * SCALE ----------
__launch_bounds__(256)
__global__ void scores_kernel(const u16* __restrict__ outp, const float* __restrict__ est,
                              float* __restrict__ wout)
{
  __shared__ float es[N_B * E_DIM];  // 48 KB
  const int tid = threadIdx.x, wv = tid >> 6, lane = tid & 63;
  const int b = blockIdx.y;
  for (int i = tid; i < N_B * E_DIM; i += 256) es[i] = est[i];
  __syncthreads();

  for (int ti = 0; ti < 16; ++ti) {
    int t = blockIdx.x * 64 + wv * 16 + ti;   // wave-uniform
    if (t >= NT) continue;
    const uint32_t* row =
        (const uint32_t*)(outp + ((size_t)b * L_SEQ + 2 + t) * E_DIM);
    float a[8];
#pragma unroll
    for (int s = 0; s < 8; ++s) a[s] = 0.f;
    for (int c = 0; c < 12; ++c) {
      uint32_t pv = row[c * 64 + lane];
      float v0 = b2f((u16)(pv & 0xFFFF)), v1 = b2f((u16)(pv >> 16));
      int idx = (c * 64 + lane) * 2;
#pragma unroll
      for (int s = 0; s < 8; ++s)
        a[s] += es[s * E_DIM + idx] * v0 + es[s * E_DIM + idx + 1] * v1;
    }
#pragma unroll
    for (int off = 32; off > 0; off >>= 1)
#pragma unroll
      for (int s = 0; s < 8; ++s) a[s] += __shfl_down(a[s], off);
    if (lane == 0) {
#pragma unroll
      for (int s = 0; s < 8; ++s)
        wout[(size_t)(b * N_B + s) * NT + t] = a[s] * SCALE;
    }
  }
}

// ---------------- softmax over t (in place on d_out weights region) ----------------
__launch_bounds__(256)
__global__ void softmax_w(float* __restrict__ wbase)
{
  float* p = wbase + (size_t)blockIdx.x * NT;  // 64 rows
  __shared__ float r1[4], r2[4];
  __shared__ float bmax, bsum;
  const int tid = threadIdx.x, wv = tid >> 6, lane = tid & 63;

  float vals[8], mx = -1e30f;
#pragma unroll
  for (int i = 0; i < 8; ++i) {
    int t = tid + i * 256;
    vals[i] = (t < NT) ? p[t] : -1e30f;
    mx = fmaxf(mx, vals[i]);
  }
#pragma unroll
  for (int off = 32; off > 0; off >>= 1) mx = fmaxf(mx, __shfl_down(mx, off));
  if (lane == 0) r1[wv] = mx;
  __syncthreads();
  if (tid == 0) bmax = fmaxf(fmaxf(r1[0], r1[1]), fmaxf(r1[2], r1[3]));
  __syncthreads();
  mx = bmax;

  float sum = 0.f;
#pragma unroll
  for (int i = 0; i < 8; ++i) {
    int t = tid + i * 256;
    if (t < NT) { vals[i] = expf(vals[i] - mx); sum += vals[i]; }
  }
#pragma unroll
  for (int off = 32; off > 0; off >>= 1) sum += __shfl_down(sum, off);
  if (lane == 0) r2[wv] = sum;
  __syncthreads();
  if (tid == 0) bsum = r2[0] + r2[1] + r2[2] + r2[3];
  __syncthreads();
  const float inv = 1.f / bsum;
#pragma unroll
  for (int i = 0; i < 8; ++i) {
    int t = tid + i * 256;
    if (t < NT) p[t] = vals[i] * inv;
  }
}

// ---------------- attended = weights @ e_actions (two-stage) ----------------
__launch_bounds__(256)
__global__ void attended_partial(const u16* __restrict__ outp, const float* __restrict__ wts,
                                 float* __restrict__ part)
{
  const int tid = threadIdx.x;
  const int e = blockIdx.x * 256 + tid;      // grid.x = 6
  const int b = blockIdx.y, z = blockIdx.z;  // 8, 4
  __shared__ float wl[8][256];
  float a[8];
#pragma unroll
  for (int s = 0; s < 8; ++s) a[s] = 0.f;

  const int tbeg = z * 512;
  const int tend = (tbeg + 512 < NT) ? tbeg + 512 : NT;
  for (int tb = tbeg; tb < tend; tb += 256) {
    const int cnt = (tend - tb < 256) ? (tend - tb) : 256;
    __syncthreads();
    for (int i = tid; i < 8 * 256; i += 256) {
      int s = i >> 8, tt = i & 255;
      wl[s][tt] = (tt < cnt) ? wts[(size_t)(b * N_B + s) * NT + tb + tt] : 0.f;
    }
    __syncthreads();
    for (int tt = 0; tt < cnt; ++tt) {
      float val = b2f(outp[((size_t)b * L_SEQ + 2 + tb + tt) * E_DIM + e]);
#pragma unroll
      for (int s = 0; s < 8; ++s) a[s] += wl[s][tt] * val;
    }
  }
#pragma unroll
  for (int s = 0; s < 8; ++s)
    part[(((size_t)z * N_B + b) * N_B + s) * E_DIM + e] = a[s];
}
__global__ void attended_reduce(const float* __restrict__ part, float* __restrict__ outp)
{
  const int i = blockIdx.x * 256 + threadIdx.x;  // 8*8*1536 = 98304
  float s = 0.f;
#pragma unroll
  for (int z = 0; z < 4; ++z) s += part[(size_t)z * N_B * N_B * E_DIM + i];
  outp[i] = s;
}

// ---------------- host launcher ----------------
extern "C" void kernel_launch(void* const* d_in, const int* in_sizes, int n_in,
                              void* d_out, int out_size, void* d_ws, size_t ws_size,
                              hipStream_t stream)
{
  (void)in_sizes; (void)n_in; (void)out_size; (void)ws_size;
  const float* x     = (const float*)d_in[0];
  const float* Wv    = (const float*)d_in[1];
  const float* Wk    = (const float*)d_in[2];
  const float* Wq    = (const float*)d_in[3];
  const float* Wo    = (const float*)d_in[4];
  const float* bo    = (const float*)d_in[5];
  const float* gamma = (const float*)d_in[6];
  const float* beta  = (const float*)d_in[7];
  float* out = (float*)d_out;

  char* ws = (char*)d_ws;
  size_t off = 0;
  auto alloc = [&](size_t bytes) -> void* {
    void* p = ws + off;
    off += (bytes + 255) & ~(size_t)255;
    return p;
  };
  const size_t ME = (size_t)16384 * E_DIM;
  const size_t WE = (size_t)E_DIM * E_DIM;
  u16*   xb     = (u16*)alloc(ME * 2);
  u16*   wqb    = (u16*)alloc(WE * 2);
  u16*   wkb    = (u16*)alloc(WE * 2);
  u16*   wvb    = (u16*)alloc(WE * 2);
  u16*   wob    = (u16*)alloc(WE * 2);
  u16*   qb     = (u16*)alloc(ME * 2);
  u16*   kb     = (u16*)alloc(ME * 2);
  u16*   vb     = (u16*)alloc(ME * 2);
  u16*   aob    = (u16*)alloc(ME * 2);   // headmix out; REUSED as bf16 LN out
  u16*   lnbufh = (u16*)alloc(ME * 2);   // pre-LN bf16 (replaces f32 lnbuf)
  float* est    = (float*)alloc((size_t)N_B * E_DIM * 4);
  float* estp   = (float*)alloc((size_t)8 * N_B * E_DIM * 4);
  float* attp   = (float*)alloc((size_t)4 * N_B * N_B * E_DIM * 4);
  // footprint smaller than R5/R7 (lnbuf f32 -> bf16) — fits.

  float* wout = out + 98304;  // weights region of d_out

  // allow 128 KB dynamic LDS (idempotent, host-side)
  hipFuncSetAttribute(reinterpret_cast<const void*>(gemm2c<0>),
                      hipFuncAttributeMaxDynamicSharedMemorySize, 131072);
  hipFuncSetAttribute(reinterpret_cast<const void*>(gemm2c<2>),
                      hipFuncAttributeMaxDynamicSharedMemorySize, 131072);

  // fused f32 -> bf16 conversions (x + 4 weights), one launch
  cvt_all<<<dim3((NXV + 4 * NWV) / 256), 256, 0, stream>>>(
      x, Wq, Wk, Wv, Wo, xb, wqb, wkb, wvb, wob);

  // q/k/v projections (one launch, z-plane selects weight/output)
  gemm2c<0><<<dim3(6, 64, 3), 512, 131072, stream>>>(
      xb, wqb, wkb, wvb, qb, kb, vb, nullptr, nullptr);

  // per-position 12x12 head-mix attention
  headmix<<<dim3(16384), 256, 0, stream>>>(qb, kb, vb, aob);

  // Wo projection + bias + residual(bf16 x) -> pre-LN bf16
  gemm2c<2><<<dim3(6, 64, 1), 512, 131072, stream>>>(
      aob, wob, wob, wob, lnbufh, lnbufh, lnbufh, bo, xb);

  // LayerNorm: bf16 -> bf16, written into aob (dead after gemm2c<2>;
  // rewritten by headmix on every replay -> deterministic)
  u16* lnh = aob;
  ln_kernel<<<dim3(16384), 256, 0, stream>>>(lnbufh, lnh, gamma, beta);

  // e_state = mean over L (bf16 reads)
  estate_partial<<<dim3(6, 8, 8), 256, 0, stream>>>(lnh, estp);
  estate_reduce<<<dim3(48), 256, 0, stream>>>(estp, est);

  // scores -> softmax (in place in d_out weights region)
  scores_kernel<<<dim3(32, 8), 256, 0, stream>>>(lnh, est, wout);
  softmax_w<<<dim3(64), 256, 0, stream>>>(wout);

  // attended
  attended_partial<<<dim3(6, 8, 4), 256, 0, stream>>>(lnh, wout, attp);
  attended_reduce<<<dim3(384), 256, 0, stream>>>(attp, out);
}

// Round 9
// 490.735 us; speedup vs baseline: 1.1944x; 1.0770x over previous
//
#include <hip/hip_runtime.h>
#include <stdint.h>

typedef unsigned short u16;
typedef __bf16 bf16_t;
typedef bf16_t bf16x8 __attribute__((ext_vector_type(8)));
typedef float f32x4 __attribute__((ext_vector_type(4)));

#define E_DIM 1536
#define N_B 8
#define L_SEQ 2048
#define NT 2046
#define SCALE 0.025515518f   // 1/sqrt(1536)
#define LN_EPS 1e-5f
#define NTILES 24            // K / 64
#define NXV 6291456          // x float4 count
#define NWV 589824           // one weight float4 count

__device__ __forceinline__ u16 f2b(float f) {
  union { float f; uint32_t u; } v; v.f = f;
  uint32_t u = v.u + 0x7FFFu + ((v.u >> 16) & 1u);  // RNE
  return (u16)(u >> 16);
}
__device__ __forceinline__ float b2f(u16 h) {
  union { uint32_t u; float f; } v; v.u = ((uint32_t)h) << 16; return v.f;
}

// async global->LDS, 16B per lane; LDS dest = wave-uniform base + lane*16
__device__ __forceinline__ void gload16(const u16* g, const bf16_t* l) {
  __builtin_amdgcn_global_load_lds((const __attribute__((address_space(1))) void*)g,
                                   (__attribute__((address_space(3))) void*)l,
                                   16, 0, 0);
}

#define BAR()   __builtin_amdgcn_s_barrier()
#define SCHB()  __builtin_amdgcn_sched_barrier(0)
#define VM4()   asm volatile("s_waitcnt vmcnt(4)" ::: "memory")
#define VM0()   asm volatile("s_waitcnt vmcnt(0)" ::: "memory")

// ---------------- fused f32 -> bf16 conversion (x + 4 weights, 1 launch) ------
__global__ void cvt_all(const float* __restrict__ x,  const float* __restrict__ Wq,
                        const float* __restrict__ Wk, const float* __restrict__ Wv,
                        const float* __restrict__ Wo,
                        u16* __restrict__ xb,  u16* __restrict__ wqb,
                        u16* __restrict__ wkb, u16* __restrict__ wvb,
                        u16* __restrict__ wob)
{
  int i = blockIdx.x * 256 + threadIdx.x;   // float4 index, grid covers exactly
  const float* src; u16* dst; int o;
  if (i < NXV)              { src = x;  dst = xb;  o = i; }
  else if (i < NXV + NWV)   { src = Wq; dst = wqb; o = i - NXV; }
  else if (i < NXV + 2*NWV) { src = Wk; dst = wkb; o = i - NXV - NWV; }
  else if (i < NXV + 3*NWV) { src = Wv; dst = wvb; o = i - NXV - 2*NWV; }
  else                      { src = Wo; dst = wob; o = i - NXV - 3*NWV; }
  float4 f = ((const float4*)src)[o];
  ushort4 u;
  u.x = f2b(f.x); u.y = f2b(f.y); u.z = f2b(f.z); u.w = f2b(f.w);
  ((ushort4*)dst)[o] = u;
}

// ---------------- 256x256 register-pipelined bf16 GEMM (R3 schedule) ----------
// FUSED=0: C = bf16(acc)  (QKV; z selects B/C)
// FUSED=2: C = bf16(acc + bias[col] + b2f(resid16[idx]))  (Wo, pre-LN bf16 out)
template<int FUSED>
__launch_bounds__(512, 2)
__global__ void gemm2c(const u16* __restrict__ Ag,
                       const u16* __restrict__ B0w, const u16* __restrict__ B1w,
                       const u16* __restrict__ B2w,
                       u16* __restrict__ C0, u16* __restrict__ C1, u16* __restrict__ C2,
                       const float* __restrict__ bias, const u16* __restrict__ resid16)
{
  extern __shared__ __attribute__((aligned(16))) bf16_t lds[];

  // --- bijective XCD remap: 24-block groups (4 row-strips x 6 col-tiles)
  const int flat = (blockIdx.z * gridDim.y + blockIdx.y) * gridDim.x + blockIdx.x;
  const int xcd = flat & 7, bb_ = flat >> 3;
  const int gl = bb_ / 24, jj = bb_ % 24;
  const int g = gl * 8 + xcd;
  const int zz = g >> 4;
  const int gy = g & 15;
  const int tx = jj >> 2;
  const int ty = gy * 4 + (jj & 3);
  const int rowA = ty * 256, colB = tx * 256;

  const u16* Bg; u16* Cb;
  if (zz == 0)      { Bg = B0w; Cb = C0; }
  else if (zz == 1) { Bg = B1w; Cb = C1; }
  else              { Bg = B2w; Cb = C2; }

  const int tid = threadIdx.x;
  const int w = tid >> 6, lane = tid & 63;
  const int wr = w >> 2, wc = w & 3;

  // fragment read addressing (swizzled slot): row=64B, slot ^= (r>>1)&3
  const int rl = lane & 15, lsl = lane >> 4;
  const int sw8 = (lsl ^ ((rl >> 1) & 3)) * 8;
  const int arow = (wr * 128 + rl) * 32 + sw8;   // + m*512 + Aregion
  const int brow = (wc * 64 + rl) * 32 + sw8;    // + n*512 + Bregion

  // staging: chunk c = ld*512+tid; r=c>>2, sp=c&3; source pre-swizzled so the
  // linear LDS dest holds the swizzled layout (rule 21).
  const int r0s = tid >> 2, sps = tid & 3;
  const int sws = (sps ^ ((r0s >> 1) & 3)) * 8;
  const size_t sA0 = (size_t)(rowA + r0s) * E_DIM + sws;
  const size_t sA1 = (size_t)(rowA + 128 + r0s) * E_DIM + sws;
  const size_t sB0 = (size_t)(colB + r0s) * E_DIM + sws;
  const size_t sB1 = (size_t)(colB + 128 + r0s) * E_DIM + sws;
  const int wb0 = w * 512, wb1 = 4096 + w * 512;   // elem offsets in region

  // LDS regions (elem offsets): A (buf,kh) = (buf*2+kh)*8192; B = 32768 + same
  f32x4 acc[8][4];
#pragma unroll
  for (int m = 0; m < 8; ++m)
#pragma unroll
    for (int n = 0; n < 4; ++n)
#pragma unroll
      for (int q = 0; q < 4; ++q) acc[m][n][q] = 0.0f;

  // ---- prologue: stage t0.kh0(4), t0.kh1(4), t1.kh0(4) in FIFO groups
  gload16(Ag + sA0,      lds + 0     + wb0);  gload16(Ag + sA1,      lds + 0     + wb1);
  gload16(Bg + sB0,      lds + 32768 + wb0);  gload16(Bg + sB1,      lds + 32768 + wb1);
  gload16(Ag + sA0 + 32, lds + 8192  + wb0);  gload16(Ag + sA1 + 32, lds + 8192  + wb1);
  gload16(Bg + sB0 + 32, lds + 40960 + wb0);  gload16(Bg + sB1 + 32, lds + 40960 + wb1);
  gload16(Ag + sA0 + 64, lds + 16384 + wb0);  gload16(Ag + sA1 + 64, lds + 16384 + wb1);
  gload16(Bg + sB0 + 64, lds + 49152 + wb0);  gload16(Bg + sB1 + 64, lds + 49152 + wb1);
  VM4();                       // t0.kh0 + t0.kh1 landed; t1.kh0 outstanding
  BAR();

  bf16x8 a0[8], b0[4], a1[8], b1[4];
  // R0 = t0.kk0
#pragma unroll
  for (int m = 0; m < 8; ++m) a0[m] = *(const bf16x8*)&lds[0 + arow + m * 512];
#pragma unroll
  for (int n = 0; n < 4; ++n) b0[n] = *(const bf16x8*)&lds[32768 + brow + n * 512];

  for (int t = 0; t < NTILES; ++t) {
    const int cur = t & 1, nxt = cur ^ 1;
    const int Ak1 = (cur * 2 + 1) * 8192, Bk1 = 32768 + (cur * 2 + 1) * 8192;
    const int AkN0 = nxt * 2 * 8192,      BkN0 = 32768 + nxt * 2 * 8192;
    const int AkN1 = (nxt * 2 + 1) * 8192, BkN1 = 32768 + (nxt * 2 + 1) * 8192;

    // ---- issue R1 = cur.kk1 fragment reads; issue g12 = (t+1).kh1
#pragma unroll
    for (int m = 0; m < 8; ++m) a1[m] = *(const bf16x8*)&lds[Ak1 + arow + m * 512];
#pragma unroll
    for (int n = 0; n < 4; ++n) b1[n] = *(const bf16x8*)&lds[Bk1 + brow + n * 512];
    if (t + 1 < NTILES) {
      const size_t ko = (size_t)(t + 1) * 64 + 32;
      gload16(Ag + sA0 + ko, lds + AkN1 + wb0);  gload16(Ag + sA1 + ko, lds + AkN1 + wb1);
      gload16(Bg + sB0 + ko, lds + BkN1 + wb0);  gload16(Bg + sB1 + ko, lds + BkN1 + wb1);
    }
    SCHB();
    // ---- MFMA cluster 0 (kk0)
    __builtin_amdgcn_s_setprio(1);
#pragma unroll
    for (int m = 0; m < 8; ++m)
#pragma unroll
      for (int n = 0; n < 4; ++n)
        acc[m][n] = __builtin_amdgcn_mfma_f32_16x16x32_bf16(a0[m], b0[n], acc[m][n], 0, 0, 0);
    __builtin_amdgcn_s_setprio(0);
    SCHB();
    if (t + 1 < NTILES) { VM4(); }   // retire (t+1).kh0
    BAR();

    // ---- issue g34 = (t+2).kh0 -> cur.kh0 (readers retired); R0' = (t+1).kk0
    if (t + 2 < NTILES) {
      const size_t ko = (size_t)(t + 2) * 64;
      gload16(Ag + sA0 + ko, lds + cur * 2 * 8192 + wb0);
      gload16(Ag + sA1 + ko, lds + cur * 2 * 8192 + wb1);
      gload16(Bg + sB0 + ko, lds + 32768 + cur * 2 * 8192 + wb0);
      gload16(Bg + sB1 + ko, lds + 32768 + cur * 2 * 8192 + wb1);
    }
    if (t + 1 < NTILES) {
#pragma unroll
      for (int m = 0; m < 8; ++m) a0[m] = *(const bf16x8*)&lds[AkN0 + arow + m * 512];
#pragma unroll
      for (int n = 0; n < 4; ++n) b0[n] = *(const bf16x8*)&lds[BkN0 + brow + n * 512];
    }
    SCHB();
    // ---- MFMA cluster 1 (kk1)
    __builtin_amdgcn_s_setprio(1);
#pragma unroll
    for (int m = 0; m < 8; ++m)
#pragma unroll
      for (int n = 0; n < 4; ++n)
        acc[m][n] = __builtin_amdgcn_mfma_f32_16x16x32_bf16(a1[m], b1[n], acc[m][n], 0, 0, 0);
    __builtin_amdgcn_s_setprio(0);
    SCHB();
    if (t + 2 < NTILES)      { VM4(); }
    else if (t + 1 < NTILES) { VM0(); }
    BAR();
  }

  // ---- epilogue: C/D layout col=lane&15, row=(lane>>4)*4+reg [m89]
  const int r0 = (lane >> 4) * 4;
#pragma unroll
  for (int m = 0; m < 8; ++m) {
#pragma unroll
    for (int n = 0; n < 4; ++n) {
      const int gcol = colB + wc * 64 + n * 16 + rl;
#pragma unroll
      for (int q = 0; q < 4; ++q) {
        const int grow = rowA + wr * 128 + m * 16 + r0 + q;
        const size_t idx = (size_t)grow * E_DIM + gcol;
        if (FUSED == 2)
          Cb[idx] = f2b(acc[m][n][q] + bias[gcol] + b2f(resid16[idx]));
        else
          Cb[idx] = f2b(acc[m][n][q]);
      }
    }
  }
}

// ---------------- per-position 12x12 head-mix attention (vectorized) ----------
__launch_bounds__(256)
__global__ void headmix(const u16* __restrict__ qb, const u16* __restrict__ kb,
                        const u16* __restrict__ vb, u16* __restrict__ aob)
{
  __shared__ float qs[12 * 132], ks2[12 * 132], vs[12 * 132];
  __shared__ float att[12][12];
  const int tid = threadIdx.x;
  const size_t base = (size_t)blockIdx.x * E_DIM;

  if (tid < 192) {   // 192 threads x 8 bf16 (16B) per array
    const int i = tid >> 4, d0 = (tid & 15) * 8, p = i * 132 + d0;
    uint4 q4 = *(const uint4*)(qb + base + tid * 8);
    uint4 k4 = *(const uint4*)(kb + base + tid * 8);
    uint4 v4 = *(const uint4*)(vb + base + tid * 8);
#pragma unroll
    for (int c = 0; c < 4; ++c) {
      uint32_t qa = (&q4.x)[c], ka = (&k4.x)[c], va = (&v4.x)[c];
      qs[p + 2*c]     = b2f((u16)(qa & 0xFFFF));
      qs[p + 2*c + 1] = b2f((u16)(qa >> 16));
      ks2[p + 2*c]     = b2f((u16)(ka & 0xFFFF));
      ks2[p + 2*c + 1] = b2f((u16)(ka >> 16));
      vs[p + 2*c]     = b2f((u16)(va & 0xFFFF));
      vs[p + 2*c + 1] = b2f((u16)(va >> 16));
    }
  }
  __syncthreads();

  if (tid < 144) {
    int i = tid / 12, j = tid % 12;
    const float4* qr = (const float4*)&qs[i * 132];
    const float4* kr = (const float4*)&ks2[j * 132];
    float s = 0.f;
#pragma unroll 8
    for (int d4 = 0; d4 < 32; ++d4) {
      float4 a = qr[d4], b = kr[d4];
      s += a.x * b.x + a.y * b.y + a.z * b.z + a.w * b.w;
    }
    att[i][j] = s * SCALE;
  }
  __syncthreads();

  if (tid < 12) {
    float mx = att[tid][0];
#pragma unroll
    for (int j = 1; j < 12; ++j) mx = fmaxf(mx, att[tid][j]);
    float ev[12], sum = 0.f;
#pragma unroll
    for (int j = 0; j < 12; ++j) { ev[j] = expf(att[tid][j] - mx); sum += ev[j]; }
    float inv = 1.f / sum;
#pragma unroll
    for (int j = 0; j < 12; ++j) att[tid][j] = ev[j] * inv;
  }
  __syncthreads();

  for (int e = tid; e < E_DIM; e += 256) {
    int i = e >> 7, d = e & 127;
    float o = 0.f;
#pragma unroll
    for (int j = 0; j < 12; ++j) o += att[i][j] * vs[j * 132 + d];
    aob[base + e] = f2b(o);
  }
}

// ---------------- LayerNorm: bf16 in -> bf16 out (u32-packed) ----------------
__launch_bounds__(256)
__global__ void ln_kernel(const u16* __restrict__ p, u16* __restrict__ ho,
                          const float* __restrict__ gamma, const float* __restrict__ beta)
{
  __shared__ float rs[4], rq[4];
  __shared__ float mean_s, rstd_s;
  const int tid = threadIdx.x, w = tid >> 6, lane = tid & 63;
  const uint32_t* row = (const uint32_t*)(p + (size_t)blockIdx.x * E_DIM);   // 768 u32
  uint32_t* orow = (uint32_t*)(ho + (size_t)blockIdx.x * E_DIM);

  float v[6], s = 0.f, sq = 0.f;
#pragma unroll
  for (int i = 0; i < 3; ++i) {
    uint32_t u = row[tid + i * 256];
    float lo = b2f((u16)(u & 0xFFFF)), hi = b2f((u16)(u >> 16));
    v[2*i] = lo; v[2*i+1] = hi;
    s += lo + hi; sq += lo * lo + hi * hi;
  }
#pragma unroll
  for (int off = 32; off > 0; off >>= 1) {
    s  += __shfl_down(s, off);
    sq += __shfl_down(sq, off);
  }
  if (lane == 0) { rs[w] = s; rq[w] = sq; }
  __syncthreads();
  if (tid == 0) {
    float S = rs[0] + rs[1] + rs[2] + rs[3];
    float Q = rq[0] + rq[1] + rq[2] + rq[3];
    float mu = S * (1.f / 1536.f);
    float var = Q * (1.f / 1536.f) - mu * mu;
    mean_s = mu; rstd_s = rsqrtf(var + LN_EPS);
  }
  __syncthreads();
  const float mu = mean_s, rstd = rstd_s;
#pragma unroll
  for (int i = 0; i < 3; ++i) {
    int j = tid + i * 256;              // u32 index; elements 2j, 2j+1
    float o0 = (v[2*i]   - mu) * rstd * gamma[2*j]   + beta[2*j];
    float o1 = (v[2*i+1] - mu) * rstd * gamma[2*j+1] + beta[2*j+1];
    orow[j] = (uint32_t)f2b(o0) | ((uint32_t)f2b(o1) << 16);
  }
}

// -------- e_state partial: full-row coalesced. grid (8 b, 32 rc) x 256 --------
// 192 active threads read 1 uint4 (8 bf16) per row; 64 rows per block.
__launch_bounds__(256)
__global__ void estate_partial(const u16* __restrict__ outp, float* __restrict__ part)
{
  const int tid = threadIdx.x;
  const int b = blockIdx.x, rc = blockIdx.y;
  if (tid >= 192) return;
  const uint4* base = (const uint4*)(outp + ((size_t)b * L_SEQ + rc * 64) * E_DIM);
  float a[8];
#pragma unroll
  for (int k = 0; k < 8; ++k) a[k] = 0.f;
  for (int r = 0; r < 64; ++r) {
    uint4 v = base[(size_t)r * 192 + tid];
#pragma unroll
    for (int c = 0; c < 4; ++c) {
      uint32_t u = (&v.x)[c];
      a[2*c]   += b2f((u16)(u & 0xFFFF));
      a[2*c+1] += b2f((u16)(u >> 16));
    }
  }
  float* dst = part + ((size_t)rc * N_B + b) * E_DIM + tid * 8;
#pragma unroll
  for (int k = 0; k < 8; ++k) dst[k] = a[k];
}
__global__ void estate_reduce(const float* __restrict__ part, float* __restrict__ est)
{
  const int i = blockIdx.x * 256 + threadIdx.x;  // 8*1536 = 12288
  if (i < N_B * E_DIM) {
    float s = 0.f;
#pragma unroll
    for (int z = 0; z < 32; ++z) s += part[(size_t)z * N_B * E_DIM + i];
    est[i] = s * (1.f / 2048.f);
  }
}

// ---------------- scores[b][s][t] = dot(e_state[s], out[b][2+t]) * SCALE ----------
__launch_bounds__(256)
__global__ void scores_kernel(const u16* __restrict__ outp, const float* __restrict__ est,
                              float* __restrict__ wout)
{
  __shared__ float es[N_B * E_DIM];  // 48 KB
  const int tid = threadIdx.x, wv = tid >> 6, lane = tid & 63;
  const int b = blockIdx.y;
  for (int i = tid; i < N_B * E_DIM; i += 256) es[i] = est[i];
  __syncthreads();

  for (int ti = 0; ti < 16; ++ti) {
    int t = blockIdx.x * 64 + wv * 16 + ti;   // wave-uniform
    if (t >= NT) continue;
    const uint32_t* row =
        (const uint32_t*)(outp + ((size_t)b * L_SEQ + 2 + t) * E_DIM);
    float a[8];
#pragma unroll
    for (int s = 0; s < 8; ++s) a[s] = 0.f;
    for (int c = 0; c < 12; ++c) {
      uint32_t pv = row[c * 64 + lane];
      float v0 = b2f((u16)(pv & 0xFFFF)), v1 = b2f((u16)(pv >> 16));
      int idx = (c * 64 + lane) * 2;
#pragma unroll
      for (int s = 0; s < 8; ++s)
        a[s] += es[s * E_DIM + idx] * v0 + es[s * E_DIM + idx + 1] * v1;
    }
#pragma unroll
    for (int off = 32; off > 0; off >>= 1)
#pragma unroll
      for (int s = 0; s < 8; ++s) a[s] += __shfl_down(a[s], off);
    if (lane == 0) {
#pragma unroll
      for (int s = 0; s < 8; ++s)
        wout[(size_t)(b * N_B + s) * NT + t] = a[s] * SCALE;
    }
  }
}

// ---------------- softmax over t (in place on d_out weights region) ----------------
__launch_bounds__(256)
__global__ void softmax_w(float* __restrict__ wbase)
{
  float* p = wbase + (size_t)blockIdx.x * NT;  // 64 rows
  __shared__ float r1[4], r2[4];
  __shared__ float bmax, bsum;
  const int tid = threadIdx.x, wv = tid >> 6, lane = tid & 63;

  float vals[8], mx = -1e30f;
#pragma unroll
  for (int i = 0; i < 8; ++i) {
    int t = tid + i * 256;
    vals[i] = (t < NT) ? p[t] : -1e30f;
    mx = fmaxf(mx, vals[i]);
  }
#pragma unroll
  for (int off = 32; off > 0; off >>= 1) mx = fmaxf(mx, __shfl_down(mx, off));
  if (lane == 0) r1[wv] = mx;
  __syncthreads();
  if (tid == 0) bmax = fmaxf(fmaxf(r1[0], r1[1]), fmaxf(r1[2], r1[3]));
  __syncthreads();
  mx = bmax;

  float sum = 0.f;
#pragma unroll
  for (int i = 0; i < 8; ++i) {
    int t = tid + i * 256;
    if (t < NT) { vals[i] = expf(vals[i] - mx); sum += vals[i]; }
  }
#pragma unroll
  for (int off = 32; off > 0; off >>= 1) sum += __shfl_down(sum, off);
  if (lane == 0) r2[wv] = sum;
  __syncthreads();
  if (tid == 0) bsum = r2[0] + r2[1] + r2[2] + r2[3];
  __syncthreads();
  const float inv = 1.f / bsum;
#pragma unroll
  for (int i = 0; i < 8; ++i) {
    int t = tid + i * 256;
    if (t < NT) p[t] = vals[i] * inv;
  }
}

// -------- attended partial: full-row coalesced. grid (8 b, 32 tc) x 256 -------
// weights tile (8s x 64t) in LDS (broadcast reads); 192 active threads read
// 1 uint4 per row; acc[8s][8e]; partial [tc][b][s][1536].
__launch_bounds__(256)
__global__ void attended_partial(const u16* __restrict__ outp, const float* __restrict__ wts,
                                 float* __restrict__ part)
{
  __shared__ float wl[8][64];
  const int tid = threadIdx.x;
  const int b = blockIdx.x, tc = blockIdx.y;
  const int t0 = tc * 64;
  const int cnt = (NT - t0 < 64) ? (NT - t0) : 64;   // last chunk: 62

  for (int i = tid; i < 8 * 64; i += 256) {
    int s = i >> 6, tt = i & 63;
    wl[s][tt] = (tt < cnt) ? wts[(size_t)(b * N_B + s) * NT + t0 + tt] : 0.f;
  }
  __syncthreads();
  if (tid >= 192) return;

  const uint4* base = (const uint4*)(outp + ((size_t)b * L_SEQ + 2 + t0) * E_DIM);
  float a[8][8];
#pragma unroll
  for (int s = 0; s < 8; ++s)
#pragma unroll
    for (int k = 0; k < 8; ++k) a[s][k] = 0.f;

  for (int tt = 0; tt < cnt; ++tt) {
    uint4 v = base[(size_t)tt * 192 + tid];
    float e[8];
#pragma unroll
    for (int c = 0; c < 4; ++c) {
      uint32_t u = (&v.x)[c];
      e[2*c]   = b2f((u16)(u & 0xFFFF));
      e[2*c+1] = b2f((u16)(u >> 16));
    }
#pragma unroll
    for (int s = 0; s < 8; ++s) {
      const float wv = wl[s][tt];
#pragma unroll
      for (int k = 0; k < 8; ++k) a[s][k] += wv * e[k];
    }
  }
#pragma unroll
  for (int s = 0; s < 8; ++s) {
    float* dst = part + (((size_t)tc * N_B + b) * N_B + s) * E_DIM + tid * 8;
#pragma unroll
    for (int k = 0; k < 8; ++k) dst[k] = a[s][k];
  }
}
__global__ void attended_reduce(const float* __restrict__ part, float* __restrict__ outp)
{
  const int i = blockIdx.x * 256 + threadIdx.x;  // 8*8*1536 = 98304
  float s = 0.f;
#pragma unroll
  for (int z = 0; z < 32; ++z) s += part[(size_t)z * N_B * N_B * E_DIM + i];
  outp[i] = s;
}

// ---------------- host launcher ----------------
extern "C" void kernel_launch(void* const* d_in, const int* in_sizes, int n_in,
                              void* d_out, int out_size, void* d_ws, size_t ws_size,
                              hipStream_t stream)
{
  (void)in_sizes; (void)n_in; (void)out_size; (void)ws_size;
  const float* x     = (const float*)d_in[0];
  const float* Wv    = (const float*)d_in[1];
  const float* Wk    = (const float*)d_in[2];
  const float* Wq    = (const float*)d_in[3];
  const float* Wo    = (const float*)d_in[4];
  const float* bo    = (const float*)d_in[5];
  const float* gamma = (const float*)d_in[6];
  const float* beta  = (const float*)d_in[7];
  float* out = (float*)d_out;

  char* ws = (char*)d_ws;
  size_t off = 0;
  auto alloc = [&](size_t bytes) -> void* {
    void* p = ws + off;
    off += (bytes + 255) & ~(size_t)255;
    return p;
  };
  const size_t ME = (size_t)16384 * E_DIM;
  const size_t WE = (size_t)E_DIM * E_DIM;
  u16*   xb     = (u16*)alloc(ME * 2);
  u16*   wqb    = (u16*)alloc(WE * 2);
  u16*   wkb    = (u16*)alloc(WE * 2);
  u16*   wvb    = (u16*)alloc(WE * 2);
  u16*   wob    = (u16*)alloc(WE * 2);
  u16*   qb     = (u16*)alloc(ME * 2);
  u16*   kb     = (u16*)alloc(ME * 2);
  u16*   vb     = (u16*)alloc(ME * 2);
  u16*   aob    = (u16*)alloc(ME * 2);   // headmix out; REUSED as bf16 LN out
  u16*   lnbufh = (u16*)alloc(ME * 2);   // pre-LN bf16
  float* est    = (float*)alloc((size_t)N_B * E_DIM * 4);
  float* estp   = (float*)alloc((size_t)32 * N_B * E_DIM * 4);            // 1.6 MB
  float* attp   = (float*)alloc((size_t)32 * N_B * N_B * E_DIM * 4);     // 12.6 MB
  // footprint ~336 MB < R1-R5's known-good ~371 MB.

  float* wout = out + 98304;  // weights region of d_out

  // allow 128 KB dynamic LDS (idempotent, host-side)
  hipFuncSetAttribute(reinterpret_cast<const void*>(gemm2c<0>),
                      hipFuncAttributeMaxDynamicSharedMemorySize, 131072);
  hipFuncSetAttribute(reinterpret_cast<const void*>(gemm2c<2>),
                      hipFuncAttributeMaxDynamicSharedMemorySize, 131072);

  // fused f32 -> bf16 conversions (x + 4 weights), one launch
  cvt_all<<<dim3((NXV + 4 * NWV) / 256), 256, 0, stream>>>(
      x, Wq, Wk, Wv, Wo, xb, wqb, wkb, wvb, wob);

  // q/k/v projections (one launch, z-plane selects weight/output)
  gemm2c<0><<<dim3(6, 64, 3), 512, 131072, stream>>>(
      xb, wqb, wkb, wvb, qb, kb, vb, nullptr, nullptr);

  // per-position 12x12 head-mix attention
  headmix<<<dim3(16384), 256, 0, stream>>>(qb, kb, vb, aob);

  // Wo projection + bias + residual(bf16 x) -> pre-LN bf16
  gemm2c<2><<<dim3(6, 64, 1), 512, 131072, stream>>>(
      aob, wob, wob, wob, lnbufh, lnbufh, lnbufh, bo, xb);

  // LayerNorm: bf16 -> bf16, into aob (dead after gemm2c<2>; rewritten by
  // headmix every replay -> deterministic)
  u16* lnh = aob;
  ln_kernel<<<dim3(16384), 256, 0, stream>>>(lnbufh, lnh, gamma, beta);

  // e_state = mean over L (full-row coalesced partials)
  estate_partial<<<dim3(8, 32), 256, 0, stream>>>(lnh, estp);
  estate_reduce<<<dim3(48), 256, 0, stream>>>(estp, est);

  // scores -> softmax (in place in d_out weights region)
  scores_kernel<<<dim3(32, 8), 256, 0, stream>>>(lnh, est, wout);
  softmax_w<<<dim3(64), 256, 0, stream>>>(wout);

  // attended (full-row coalesced partials)
  attended_partial<<<dim3(8, 32), 256, 0, stream>>>(lnh, wout, attp);
  attended_reduce<<<dim3(384), 256, 0, stream>>>(attp, out);
}